// Round 8
// baseline (2014.198 us; speedup 1.0000x reference)
//
#include <hip/hip_runtime.h>
#include <math.h>

#define BATCH 8
#define SEQ   2048
#define CDIM  768
#define HDIM  64
#define QROWS 32
#define NSB   (SEQ / 64)
#define CAP   24
#define MARGIN 1e-2f
// exact: (raw * -1e14) * 0.125 == raw * (-1e14 * 0.125) (pow-2 scale commutes w/ rounding)
#define MASKC (-99999999999999.0 * 0.125)
#define SENTINEL 0x7FC0DEADu   // NaN payload: flags honest/ambiguous rows inside d_out

// ---------------------------------------------------------------- projection
// q,k fp64 (np-matching score ordering); v fp32.
__global__ __launch_bounds__(256) void qkv_proj_kernel(
    const float* __restrict__ x,
    const float* __restrict__ Wk,
    const float* __restrict__ Wq,
    const float* __restrict__ Wv,
    double* __restrict__ qd,
    double* __restrict__ kd,
    float*  __restrict__ vf)
{
    __shared__ float xs[32][68];
    __shared__ float wqs[64 * 64];
    __shared__ float wks[64 * 64];
    __shared__ float wvs[64 * 64];

    const int tid = threadIdx.x;
    const int tx  = tid & 15;
    const int ty  = tid >> 4;
    const size_t row0 = (size_t)blockIdx.x * 32;

    double qa[2][4] = {{0, 0, 0, 0}, {0, 0, 0, 0}};
    double ka[2][4] = {{0, 0, 0, 0}, {0, 0, 0, 0}};
    float  va[2][4] = {{0, 0, 0, 0}, {0, 0, 0, 0}};

    for (int cc = 0; cc < CDIM; cc += 64) {
        __syncthreads();
        #pragma unroll
        for (int it = 0; it < 2; ++it) {
            const int t  = tid + it * 256;
            const int r  = t >> 4;
            const int c4 = t & 15;
            const float4 v4 = *reinterpret_cast<const float4*>(
                &x[(row0 + r) * CDIM + cc + c4 * 4]);
            *reinterpret_cast<float4*>(&xs[r][c4 * 4]) = v4;
        }
        {
            const float4* wqg = reinterpret_cast<const float4*>(&Wq[(size_t)cc * HDIM]);
            const float4* wkg = reinterpret_cast<const float4*>(&Wk[(size_t)cc * HDIM]);
            const float4* wvg = reinterpret_cast<const float4*>(&Wv[(size_t)cc * HDIM]);
            float4* wql = reinterpret_cast<float4*>(wqs);
            float4* wkl = reinterpret_cast<float4*>(wks);
            float4* wvl = reinterpret_cast<float4*>(wvs);
            #pragma unroll
            for (int it = 0; it < 4; ++it) {
                const int t = tid + it * 256;
                wql[t] = wqg[t];
                wkl[t] = wkg[t];
                wvl[t] = wvg[t];
            }
        }
        __syncthreads();
        #pragma unroll 4
        for (int c = 0; c < 64; ++c) {
            const float4 wq4 = *reinterpret_cast<const float4*>(&wqs[c * 64 + tx * 4]);
            const float4 wk4 = *reinterpret_cast<const float4*>(&wks[c * 64 + tx * 4]);
            const float4 wv4 = *reinterpret_cast<const float4*>(&wvs[c * 64 + tx * 4]);
            #pragma unroll
            for (int i = 0; i < 2; ++i) {
                const float  xv = xs[ty * 2 + i][c];
                const double xd = (double)xv;
                qa[i][0] += xd * (double)wq4.x;
                qa[i][1] += xd * (double)wq4.y;
                qa[i][2] += xd * (double)wq4.z;
                qa[i][3] += xd * (double)wq4.w;
                ka[i][0] += xd * (double)wk4.x;
                ka[i][1] += xd * (double)wk4.y;
                ka[i][2] += xd * (double)wk4.z;
                ka[i][3] += xd * (double)wk4.w;
                va[i][0] += xv * wv4.x;
                va[i][1] += xv * wv4.y;
                va[i][2] += xv * wv4.z;
                va[i][3] += xv * wv4.w;
            }
        }
    }
    #pragma unroll
    for (int i = 0; i < 2; ++i) {
        const size_t row = row0 + ty * 2 + i;
        *reinterpret_cast<double2*>(&qd[row * HDIM + tx * 4])     = make_double2(qa[i][0], qa[i][1]);
        *reinterpret_cast<double2*>(&qd[row * HDIM + tx * 4 + 2]) = make_double2(qa[i][2], qa[i][3]);
        *reinterpret_cast<double2*>(&kd[row * HDIM + tx * 4])     = make_double2(ka[i][0], ka[i][1]);
        *reinterpret_cast<double2*>(&kd[row * HDIM + tx * 4 + 2]) = make_double2(ka[i][2], ka[i][3]);
        *reinterpret_cast<float4*>(&vf[row * HDIM + tx * 4]) =
            make_float4(va[i][0], va[i][1], va[i][2], va[i][3]);
    }
}

// ---------------------------------------------------------------- argmin engine
// grid (64,8). tb = (by&4)? 63-bx : bx  -> blocks i, i+256 (co-CU) sum to uniform
// load. fp32 future-only scores; online running-min; candidate capture with the
// invariant: s32 > runmin+MARGIN at visit time => s32 > finalmin+MARGIN (runmin
// is non-increasing), so candidates provably contain the true fp64 argmin
// (|s32 - raw64| <= ~6e-4 << MARGIN). Refinement: exact fp64 dots on candidates.
__global__ __launch_bounds__(256, 4) void argmin_kernel(
    const double* __restrict__ qd,
    const double* __restrict__ kd,
    const float*  __restrict__ vf,
    float* __restrict__ out)
{
    __shared__ float qf[QROWS][68];
    __shared__ float kf[64][68];
    __shared__ unsigned cnt[QROWS];
    __shared__ unsigned short cand[QROWS][CAP];

    const int tid = threadIdx.x;
    const int tx  = tid & 15;       // score cols 16j + tx (consecutive -> conflict-free)
    const int ty  = tid >> 4;       // score rows 2ty, 2ty+1
    const int bx  = blockIdx.x, by = blockIdx.y;
    const int tb  = (by & 4) ? (63 - bx) : bx;
    const int b   = by;
    const int r0  = tb * QROWS;
    const int sb0 = tb >> 1;        // first s-block containing any future col

    // stage qf (fp64 -> fp32)
    {
        const double* qsrc = qd + ((size_t)b * SEQ + r0) * HDIM;
        #pragma unroll
        for (int it = 0; it < 8; ++it) {
            const int idx = tid + it * 256;
            qf[idx >> 6][idx & 63] = (float)qsrc[(idx >> 6) * HDIM + (idx & 63)];
        }
    }
    if (tid < QROWS) cnt[tid] = 0;

    const int c2 = tid & 31;
    const int rb = tid >> 5;
    double2 kreg[8];
    {
        const double* ks = kd + ((size_t)b * SEQ + sb0 * 64) * HDIM;
        #pragma unroll
        for (int it = 0; it < 8; ++it)
            kreg[it] = *reinterpret_cast<const double2*>(
                &ks[(size_t)(rb + it * 8) * HDIM + 2 * c2]);
    }
    #pragma unroll
    for (int it = 0; it < 8; ++it) {
        const int r = rb + it * 8;
        kf[r][2 * c2]     = (float)kreg[it].x;
        kf[r][2 * c2 + 1] = (float)kreg[it].y;
    }
    __syncthreads();

    float mrun[2] = {3.0e38f, 3.0e38f};

    for (int sb = sb0; sb < NSB; ++sb) {
        if (sb + 1 < NSB) {     // T14: issue next k-tile loads under compute
            const double* ks = kd + ((size_t)b * SEQ + (size_t)(sb + 1) * 64) * HDIM;
            #pragma unroll
            for (int it = 0; it < 8; ++it)
                kreg[it] = *reinterpret_cast<const double2*>(
                    &ks[(size_t)(rb + it * 8) * HDIM + 2 * c2]);
        }

        float s[2][4] = {{0.f, 0.f, 0.f, 0.f}, {0.f, 0.f, 0.f, 0.f}};
        #pragma unroll
        for (int d4 = 0; d4 < 16; ++d4) {
            const float4 q0 = *reinterpret_cast<const float4*>(&qf[2 * ty][4 * d4]);
            const float4 q1 = *reinterpret_cast<const float4*>(&qf[2 * ty + 1][4 * d4]);
            #pragma unroll
            for (int j = 0; j < 4; ++j) {
                const float4 kv = *reinterpret_cast<const float4*>(&kf[16 * j + tx][4 * d4]);
                s[0][j] += q0.x * kv.x + q0.y * kv.y + q0.z * kv.z + q0.w * kv.w;
                s[1][j] += q1.x * kv.x + q1.y * kv.y + q1.z * kv.z + q1.w * kv.w;
            }
        }

        #pragma unroll
        for (int i = 0; i < 2; ++i) {
            const int rloc = 2 * ty + i;
            const int rg   = r0 + rloc;
            float sm[4];
            float tmin = 3.0e38f;
            #pragma unroll
            for (int j = 0; j < 4; ++j) {
                const int col = sb * 64 + 16 * j + tx;
                sm[j] = (col > rg) ? s[i][j] : 3.0e38f;   // FUTURE only
                tmin = fminf(tmin, sm[j]);
            }
            #pragma unroll
            for (int off = 8; off > 0; off >>= 1)
                tmin = fminf(tmin, __shfl_xor(tmin, off, 16));
            const float mnew = fminf(mrun[i], tmin);
            mrun[i] = mnew;
            const float thr = mnew + MARGIN;
            #pragma unroll
            for (int j = 0; j < 4; ++j) {
                if (sm[j] <= thr) {
                    const unsigned slot = atomicAdd(&cnt[rloc], 1u);
                    if (slot < CAP)
                        cand[rloc][slot] = (unsigned short)(sb * 64 + 16 * j + tx);
                }
            }
        }
        __syncthreads();              // kf reads done
        if (sb + 1 < NSB) {
            #pragma unroll
            for (int it = 0; it < 8; ++it) {
                const int r = rb + it * 8;
                kf[r][2 * c2]     = (float)kreg[it].x;
                kf[r][2 * c2 + 1] = (float)kreg[it].y;
            }
            __syncthreads();
        }
    }
    __syncthreads();                  // cand/cnt visible to refinement mapping

    // ---- refinement: 8 lanes per row, exact fp64 dots on candidates
    const int row = tid >> 3, l8 = tid & 7;
    const int rg  = r0 + row;
    const unsigned n_raw = cnt[row];
    const int  n   = (n_raw < CAP) ? (int)n_raw : CAP;
    const bool ovf = n_raw > CAP;
    double min1 = 1.0e300, min2 = 1.0e300;
    int amin = -1;
    const double* qrow = qd + ((size_t)b * SEQ + rg) * HDIM;
    for (int c = 0; c < n; ++c) {
        const int col = cand[row][c];
        const double* krow = kd + ((size_t)b * SEQ + col) * HDIM;
        double part = 0.0;
        #pragma unroll
        for (int dd = 0; dd < 8; ++dd)
            part += qrow[8 * l8 + dd] * krow[8 * l8 + dd];
        #pragma unroll
        for (int off = 4; off > 0; off >>= 1)
            part += __shfl_xor(part, off, 8);
        if (part < min1) { min2 = min1; min1 = part; amin = col; }
        else if (part < min2) { min2 = part; }
    }
    // honest (no negative future / empty future), ambiguous tie, edge regime, or
    // overflow -> exact-row fallback via NaN sentinel in out[rg][0].
    const bool flag = (n == 0) || ovf || (min1 > -1e-10) || ((min2 - min1) < 1e-11);
    float* orow = out + ((size_t)b * SEQ + rg) * HDIM;
    if (flag) {
        if (l8 == 0) orow[0] = __uint_as_float(SENTINEL);
    } else {
        const float* vrow = vf + ((size_t)b * SEQ + amin) * HDIM;
        const float4 v0 = *reinterpret_cast<const float4*>(&vrow[8 * l8]);
        const float4 v1 = *reinterpret_cast<const float4*>(&vrow[8 * l8 + 4]);
        *reinterpret_cast<float4*>(&orow[8 * l8])     = v0;
        *reinterpret_cast<float4*>(&orow[8 * l8 + 4]) = v1;
    }
}

// ---------------------------------------------------------------- exact-row fallback
// Full fp64 reference evaluation of flagged rows (expected ~2/batch). Bit-faithful
// logits (mask folded), fp64 max, honest softmax, p-weighted V sum.
__global__ __launch_bounds__(256) void exact_kernel(
    const double* __restrict__ qd,
    const double* __restrict__ kd,
    const float*  __restrict__ vf,
    float* __restrict__ out)
{
    __shared__ double qrow[HDIM];
    __shared__ float  pbuf[SEQ];
    __shared__ float  outacc[4][HDIM];
    __shared__ double mred[4];
    __shared__ float  psred[4];

    const int tid  = threadIdx.x;
    const int wid  = tid >> 6, lane = tid & 63;
    const int r0   = blockIdx.x * 64;
    const int b    = blockIdx.y;

    for (int r = 0; r < 64; ++r) {
        const int rg = r0 + r;
        float* orow = out + ((size_t)b * SEQ + rg) * HDIM;
        if (__float_as_uint(orow[0]) != SENTINEL) continue;   // uniform branch

        if (tid < HDIM) qrow[tid] = qd[((size_t)b * SEQ + rg) * HDIM + tid];
        __syncthreads();

        double lg[8];
        double mymax = -1.0e300;
        #pragma unroll
        for (int it = 0; it < 8; ++it) {
            const int col = tid + it * 256;
            const double* kr = kd + ((size_t)b * SEQ + col) * HDIM;
            double raw = 0.0;
            for (int d = 0; d < HDIM; ++d) raw += qrow[d] * kr[d];
            lg[it] = raw * ((col <= rg) ? 0.125 : MASKC);
            mymax = fmax(mymax, lg[it]);
        }
        #pragma unroll
        for (int off = 32; off > 0; off >>= 1)
            mymax = fmax(mymax, __shfl_xor(mymax, off, 64));
        if (lane == 0) mred[wid] = mymax;
        __syncthreads();
        const double M = fmax(fmax(mred[0], mred[1]), fmax(mred[2], mred[3]));

        float mypsum = 0.f;
        #pragma unroll
        for (int it = 0; it < 8; ++it) {
            const int col = tid + it * 256;
            const double dl = lg[it] - M;
            const float p = (dl < -80.0) ? 0.f : (float)exp(dl);
            pbuf[col] = p;
            mypsum += p;
        }
        #pragma unroll
        for (int off = 32; off > 0; off >>= 1)
            mypsum += __shfl_xor(mypsum, off, 64);
        if (lane == 0) psred[wid] = mypsum;
        __syncthreads();
        const float PS = psred[0] + psred[1] + psred[2] + psred[3];

        const int d = tid & 63, chunk = tid >> 6;
        float acc = 0.f;
        for (int cc = 0; cc < 512; ++cc) {
            const int col = chunk * 512 + cc;
            acc += pbuf[col] * vf[((size_t)b * SEQ + col) * HDIM + d];
        }
        outacc[chunk][d] = acc;
        __syncthreads();
        if (tid < HDIM)
            orow[tid] = (outacc[0][tid] + outacc[1][tid] +
                         outacc[2][tid] + outacc[3][tid]) / PS;
        __syncthreads();
    }
}

extern "C" void kernel_launch(void* const* d_in, const int* in_sizes, int n_in,
                              void* d_out, int out_size, void* d_ws, size_t ws_size,
                              hipStream_t stream)
{
    const float* x  = (const float*)d_in[0];
    const float* Wk = (const float*)d_in[1];
    const float* Wq = (const float*)d_in[2];
    const float* Wv = (const float*)d_in[3];
    float* out = (float*)d_out;

    // workspace: q fp64 (8 MB) | k fp64 (8 MB) | v fp32 (4 MB) — proven 20 MB layout
    double* qd = (double*)d_ws;
    double* kd = qd + (size_t)BATCH * SEQ * HDIM;
    float*  vf = (float*)(kd + (size_t)BATCH * SEQ * HDIM);

    qkv_proj_kernel<<<dim3(512), dim3(256), 0, stream>>>(x, Wk, Wq, Wv, qd, kd, vf);
    argmin_kernel<<<dim3(64, BATCH), dim3(256), 0, stream>>>(qd, kd, vf, out);
    exact_kernel<<<dim3(SEQ / 64, BATCH), dim3(256), 0, stream>>>(qd, kd, vf, out);
}

// Round 9
// 1663.410 us; speedup vs baseline: 1.2109x; 1.2109x over previous
//
#include <hip/hip_runtime.h>
#include <math.h>

#define BATCH 8
#define SEQ   2048
#define CDIM  768
#define HDIM  64
#define QROWS 32
#define NSB   (SEQ / 64)
#define CAP   24
#define MARGIN 1e-2f
// exact: (raw * -1e14) * 0.125 == raw * (-1e14 * 0.125) (pow-2 scale commutes w/ rounding)
#define MASKC (-99999999999999.0 * 0.125)
#define SENTINEL 0x7FC0DEADu   // NaN payload: flags honest/ambiguous rows inside d_out

// ---------------------------------------------------------------- projection
// q,k fp64 (np-matching score ordering); v fp32.  (round-8 proven, unchanged)
__global__ __launch_bounds__(256) void qkv_proj_kernel(
    const float* __restrict__ x,
    const float* __restrict__ Wk,
    const float* __restrict__ Wq,
    const float* __restrict__ Wv,
    double* __restrict__ qd,
    double* __restrict__ kd,
    float*  __restrict__ vf)
{
    __shared__ float xs[32][68];
    __shared__ float wqs[64 * 64];
    __shared__ float wks[64 * 64];
    __shared__ float wvs[64 * 64];

    const int tid = threadIdx.x;
    const int tx  = tid & 15;
    const int ty  = tid >> 4;
    const size_t row0 = (size_t)blockIdx.x * 32;

    double qa[2][4] = {{0, 0, 0, 0}, {0, 0, 0, 0}};
    double ka[2][4] = {{0, 0, 0, 0}, {0, 0, 0, 0}};
    float  va[2][4] = {{0, 0, 0, 0}, {0, 0, 0, 0}};

    for (int cc = 0; cc < CDIM; cc += 64) {
        __syncthreads();
        #pragma unroll
        for (int it = 0; it < 2; ++it) {
            const int t  = tid + it * 256;
            const int r  = t >> 4;
            const int c4 = t & 15;
            const float4 v4 = *reinterpret_cast<const float4*>(
                &x[(row0 + r) * CDIM + cc + c4 * 4]);
            *reinterpret_cast<float4*>(&xs[r][c4 * 4]) = v4;
        }
        {
            const float4* wqg = reinterpret_cast<const float4*>(&Wq[(size_t)cc * HDIM]);
            const float4* wkg = reinterpret_cast<const float4*>(&Wk[(size_t)cc * HDIM]);
            const float4* wvg = reinterpret_cast<const float4*>(&Wv[(size_t)cc * HDIM]);
            float4* wql = reinterpret_cast<float4*>(wqs);
            float4* wkl = reinterpret_cast<float4*>(wks);
            float4* wvl = reinterpret_cast<float4*>(wvs);
            #pragma unroll
            for (int it = 0; it < 4; ++it) {
                const int t = tid + it * 256;
                wql[t] = wqg[t];
                wkl[t] = wkg[t];
                wvl[t] = wvg[t];
            }
        }
        __syncthreads();
        #pragma unroll 4
        for (int c = 0; c < 64; ++c) {
            const float4 wq4 = *reinterpret_cast<const float4*>(&wqs[c * 64 + tx * 4]);
            const float4 wk4 = *reinterpret_cast<const float4*>(&wks[c * 64 + tx * 4]);
            const float4 wv4 = *reinterpret_cast<const float4*>(&wvs[c * 64 + tx * 4]);
            #pragma unroll
            for (int i = 0; i < 2; ++i) {
                const float  xv = xs[ty * 2 + i][c];
                const double xd = (double)xv;
                qa[i][0] += xd * (double)wq4.x;
                qa[i][1] += xd * (double)wq4.y;
                qa[i][2] += xd * (double)wq4.z;
                qa[i][3] += xd * (double)wq4.w;
                ka[i][0] += xd * (double)wk4.x;
                ka[i][1] += xd * (double)wk4.y;
                ka[i][2] += xd * (double)wk4.z;
                ka[i][3] += xd * (double)wk4.w;
                va[i][0] += xv * wv4.x;
                va[i][1] += xv * wv4.y;
                va[i][2] += xv * wv4.z;
                va[i][3] += xv * wv4.w;
            }
        }
    }
    #pragma unroll
    for (int i = 0; i < 2; ++i) {
        const size_t row = row0 + ty * 2 + i;
        *reinterpret_cast<double2*>(&qd[row * HDIM + tx * 4])     = make_double2(qa[i][0], qa[i][1]);
        *reinterpret_cast<double2*>(&qd[row * HDIM + tx * 4 + 2]) = make_double2(qa[i][2], qa[i][3]);
        *reinterpret_cast<double2*>(&kd[row * HDIM + tx * 4])     = make_double2(ka[i][0], ka[i][1]);
        *reinterpret_cast<double2*>(&kd[row * HDIM + tx * 4 + 2]) = make_double2(ka[i][2], ka[i][3]);
        *reinterpret_cast<float4*>(&vf[row * HDIM + tx * 4]) =
            make_float4(va[i][0], va[i][1], va[i][2], va[i][3]);
    }
}

// ---------------------------------------------------------------- argmin engine
// fp32 future-only scores; online running-min; candidate capture (provably
// complete: discard only when s32 > runmin+MARGIN, runmin non-increasing,
// fp32 dot error ~2e-4 << MARGIN). Refinement: exact fp64 dots on candidates.
// Spill-proof: no register state held across barriers; LDS double-buffered K.
__global__ __launch_bounds__(256, 3) void argmin_kernel(
    const double* __restrict__ qd,
    const double* __restrict__ kd,
    const float*  __restrict__ vf,
    float* __restrict__ out)
{
    __shared__ float qf[QROWS][68];
    __shared__ float kf[2][64][68];
    __shared__ unsigned cnt[QROWS];
    __shared__ unsigned short cand[QROWS][CAP];

    const int tid = threadIdx.x;
    const int tx  = tid & 15;       // score cols 16j + tx (consecutive -> conflict-free)
    const int ty  = tid >> 4;       // score rows 2ty, 2ty+1
    const int bx  = blockIdx.x, by = blockIdx.y;
    const int tb  = (by & 4) ? (63 - bx) : bx;   // co-CU pairs sum to uniform load
    const int b   = by;
    const int r0  = tb * QROWS;
    const int sb0 = tb >> 1;        // first s-block containing any future col

    // stage qf (fp64 -> fp32, coalesced)
    {
        const double* qsrc = qd + ((size_t)b * SEQ + r0) * HDIM;
        #pragma unroll
        for (int it = 0; it < 8; ++it) {
            const int idx = tid + it * 256;
            qf[idx >> 6][idx & 63] = (float)qsrc[(idx >> 6) * HDIM + (idx & 63)];
        }
    }
    if (tid < QROWS) cnt[tid] = 0;

    const int c2 = tid & 31;
    const int rb = tid >> 5;
    // stage kf[0] = tile sb0 (load -> immediate LDS write, transient regs only)
    {
        const double* ks = kd + ((size_t)b * SEQ + (size_t)sb0 * 64) * HDIM;
        #pragma unroll
        for (int it = 0; it < 8; ++it) {
            const int r = rb + it * 8;
            const double2 v2 = *reinterpret_cast<const double2*>(
                &ks[(size_t)r * HDIM + 2 * c2]);
            kf[0][r][2 * c2]     = (float)v2.x;
            kf[0][r][2 * c2 + 1] = (float)v2.y;
        }
    }
    __syncthreads();

    float mrun[2] = {3.0e38f, 3.0e38f};
    int cur = 0;

    for (int sb = sb0; sb < NSB; ++sb) {
        // stage next tile into the OTHER buffer (no pre-write barrier needed;
        // loads issue first, compute below overlaps their latency)
        if (sb + 1 < NSB) {
            const double* ks = kd + ((size_t)b * SEQ + (size_t)(sb + 1) * 64) * HDIM;
            #pragma unroll
            for (int it = 0; it < 8; ++it) {
                const int r = rb + it * 8;
                const double2 v2 = *reinterpret_cast<const double2*>(
                    &ks[(size_t)r * HDIM + 2 * c2]);
                kf[cur ^ 1][r][2 * c2]     = (float)v2.x;
                kf[cur ^ 1][r][2 * c2 + 1] = (float)v2.y;
            }
        }

        // ---- fp32 scores: s[i][j] = q[2ty+i] . k[16j+tx]
        float s[2][4] = {{0.f, 0.f, 0.f, 0.f}, {0.f, 0.f, 0.f, 0.f}};
        #pragma unroll
        for (int d4 = 0; d4 < 16; ++d4) {
            const float4 q0 = *reinterpret_cast<const float4*>(&qf[2 * ty][4 * d4]);
            const float4 q1 = *reinterpret_cast<const float4*>(&qf[2 * ty + 1][4 * d4]);
            #pragma unroll
            for (int j = 0; j < 4; ++j) {
                const float4 kv = *reinterpret_cast<const float4*>(&kf[cur][16 * j + tx][4 * d4]);
                s[0][j] += q0.x * kv.x + q0.y * kv.y + q0.z * kv.z + q0.w * kv.w;
                s[1][j] += q1.x * kv.x + q1.y * kv.y + q1.z * kv.z + q1.w * kv.w;
            }
        }

        // ---- future-only running min + candidate capture
        #pragma unroll
        for (int i = 0; i < 2; ++i) {
            const int rloc = 2 * ty + i;
            const int rg   = r0 + rloc;
            float sm[4];
            float tmin = 3.0e38f;
            #pragma unroll
            for (int j = 0; j < 4; ++j) {
                const int col = sb * 64 + 16 * j + tx;
                sm[j] = (col > rg) ? s[i][j] : 3.0e38f;   // FUTURE only
                tmin = fminf(tmin, sm[j]);
            }
            #pragma unroll
            for (int off = 8; off > 0; off >>= 1)
                tmin = fminf(tmin, __shfl_xor(tmin, off, 16));
            const float mnew = fminf(mrun[i], tmin);
            mrun[i] = mnew;
            const float thr = mnew + MARGIN;
            #pragma unroll
            for (int j = 0; j < 4; ++j) {
                if (sm[j] <= thr) {
                    const unsigned slot = atomicAdd(&cnt[rloc], 1u);
                    if (slot < CAP)
                        cand[rloc][slot] = (unsigned short)(sb * 64 + 16 * j + tx);
                }
            }
        }
        __syncthreads();   // kf[cur] reads + kf[cur^1] writes both complete
        cur ^= 1;
    }

    // ---- refinement: 8 lanes per row, exact fp64 dots on candidates
    const int row = tid >> 3, l8 = tid & 7;
    const int rg  = r0 + row;
    const unsigned n_raw = cnt[row];
    const int  n   = (n_raw < CAP) ? (int)n_raw : CAP;
    const bool ovf = n_raw > CAP;
    double min1 = 1.0e300, min2 = 1.0e300;
    int amin = -1;
    const double* qrow = qd + ((size_t)b * SEQ + rg) * HDIM;
    for (int c = 0; c < n; ++c) {
        const int col = cand[row][c];
        const double* krow = kd + ((size_t)b * SEQ + col) * HDIM;
        double part = 0.0;
        #pragma unroll
        for (int dd = 0; dd < 8; ++dd)
            part += qrow[8 * l8 + dd] * krow[8 * l8 + dd];
        #pragma unroll
        for (int off = 4; off > 0; off >>= 1)
            part += __shfl_xor(part, off, 8);
        if (part < min1) { min2 = min1; min1 = part; amin = col; }
        else if (part < min2) { min2 = part; }
    }
    // honest (no sufficiently-negative future / empty future), ambiguous tie,
    // or overflow -> exact-row fallback via NaN sentinel in out[rg][0].
    const bool flag = (n == 0) || ovf || (min1 > -1e-10) || ((min2 - min1) < 1e-11);
    float* orow = out + ((size_t)b * SEQ + rg) * HDIM;
    if (flag) {
        if (l8 == 0) orow[0] = __uint_as_float(SENTINEL);
    } else {
        const float* vrow = vf + ((size_t)b * SEQ + amin) * HDIM;
        const float4 v0 = *reinterpret_cast<const float4*>(&vrow[8 * l8]);
        const float4 v1 = *reinterpret_cast<const float4*>(&vrow[8 * l8 + 4]);
        *reinterpret_cast<float4*>(&orow[8 * l8])     = v0;
        *reinterpret_cast<float4*>(&orow[8 * l8 + 4]) = v1;
    }
}

// ---------------------------------------------------------------- exact-row fallback
// Full fp64 reference evaluation of flagged rows (expected ~2/batch).
__global__ __launch_bounds__(256) void exact_kernel(
    const double* __restrict__ qd,
    const double* __restrict__ kd,
    const float*  __restrict__ vf,
    float* __restrict__ out)
{
    __shared__ double qrow[HDIM];
    __shared__ float  pbuf[SEQ];
    __shared__ float  outacc[4][HDIM];
    __shared__ double mred[4];
    __shared__ float  psred[4];

    const int tid  = threadIdx.x;
    const int wid  = tid >> 6, lane = tid & 63;
    const int r0   = blockIdx.x * 64;
    const int b    = blockIdx.y;

    for (int r = 0; r < 64; ++r) {
        const int rg = r0 + r;
        float* orow = out + ((size_t)b * SEQ + rg) * HDIM;
        if (__float_as_uint(orow[0]) != SENTINEL) continue;   // uniform branch

        if (tid < HDIM) qrow[tid] = qd[((size_t)b * SEQ + rg) * HDIM + tid];
        __syncthreads();

        double lg[8];
        double mymax = -1.0e300;
        #pragma unroll
        for (int it = 0; it < 8; ++it) {
            const int col = tid + it * 256;
            const double* kr = kd + ((size_t)b * SEQ + col) * HDIM;
            double raw = 0.0;
            for (int d = 0; d < HDIM; ++d) raw += qrow[d] * kr[d];
            lg[it] = raw * ((col <= rg) ? 0.125 : MASKC);
            mymax = fmax(mymax, lg[it]);
        }
        #pragma unroll
        for (int off = 32; off > 0; off >>= 1)
            mymax = fmax(mymax, __shfl_xor(mymax, off, 64));
        if (lane == 0) mred[wid] = mymax;
        __syncthreads();
        const double M = fmax(fmax(mred[0], mred[1]), fmax(mred[2], mred[3]));

        float mypsum = 0.f;
        #pragma unroll
        for (int it = 0; it < 8; ++it) {
            const int col = tid + it * 256;
            const double dl = lg[it] - M;
            const float p = (dl < -80.0) ? 0.f : (float)exp(dl);
            pbuf[col] = p;
            mypsum += p;
        }
        #pragma unroll
        for (int off = 32; off > 0; off >>= 1)
            mypsum += __shfl_xor(mypsum, off, 64);
        if (lane == 0) psred[wid] = mypsum;
        __syncthreads();
        const float PS = psred[0] + psred[1] + psred[2] + psred[3];

        const int d = tid & 63, chunk = tid >> 6;
        float acc = 0.f;
        for (int cc = 0; cc < 512; ++cc) {
            const int col = chunk * 512 + cc;
            acc += pbuf[col] * vf[((size_t)b * SEQ + col) * HDIM + d];
        }
        outacc[chunk][d] = acc;
        __syncthreads();
        if (tid < HDIM)
            orow[tid] = (outacc[0][tid] + outacc[1][tid] +
                         outacc[2][tid] + outacc[3][tid]) / PS;
        __syncthreads();
    }
}

extern "C" void kernel_launch(void* const* d_in, const int* in_sizes, int n_in,
                              void* d_out, int out_size, void* d_ws, size_t ws_size,
                              hipStream_t stream)
{
    const float* x  = (const float*)d_in[0];
    const float* Wk = (const float*)d_in[1];
    const float* Wq = (const float*)d_in[2];
    const float* Wv = (const float*)d_in[3];
    float* out = (float*)d_out;

    // workspace: q fp64 (8 MB) | k fp64 (8 MB) | v fp32 (4 MB) — proven 20 MB layout
    double* qd = (double*)d_ws;
    double* kd = qd + (size_t)BATCH * SEQ * HDIM;
    float*  vf = (float*)(kd + (size_t)BATCH * SEQ * HDIM);

    qkv_proj_kernel<<<dim3(512), dim3(256), 0, stream>>>(x, Wk, Wq, Wv, qd, kd, vf);
    argmin_kernel<<<dim3(64, BATCH), dim3(256), 0, stream>>>(qd, kd, vf, out);
    exact_kernel<<<dim3(SEQ / 64, BATCH), dim3(256), 0, stream>>>(qd, kd, vf, out);
}

// Round 10
// 1558.919 us; speedup vs baseline: 1.2920x; 1.0670x over previous
//
#include <hip/hip_runtime.h>
#include <math.h>

#define BATCH 8
#define SEQ   2048
#define CDIM  768
#define HDIM  64
#define QROWS 32
#define NSB   (SEQ / 64)
#define CAP   24
#define MARGIN 1e-2f
// exact: (raw * -1e14) * 0.125 == raw * (-1e14 * 0.125) (pow-2 scale commutes w/ rounding)
#define MASKC (-99999999999999.0 * 0.125)
#define SENTINEL 0x7FC0DEADu   // NaN payload: flags honest/ambiguous rows inside d_out

// ---------------------------------------------------------------- projection
// q,k fp64 (np-matching score ordering); v fp32.  (round-8/9 proven, unchanged)
__global__ __launch_bounds__(256) void qkv_proj_kernel(
    const float* __restrict__ x,
    const float* __restrict__ Wk,
    const float* __restrict__ Wq,
    const float* __restrict__ Wv,
    double* __restrict__ qd,
    double* __restrict__ kd,
    float*  __restrict__ vf)
{
    __shared__ float xs[32][68];
    __shared__ float wqs[64 * 64];
    __shared__ float wks[64 * 64];
    __shared__ float wvs[64 * 64];

    const int tid = threadIdx.x;
    const int tx  = tid & 15;
    const int ty  = tid >> 4;
    const size_t row0 = (size_t)blockIdx.x * 32;

    double qa[2][4] = {{0, 0, 0, 0}, {0, 0, 0, 0}};
    double ka[2][4] = {{0, 0, 0, 0}, {0, 0, 0, 0}};
    float  va[2][4] = {{0, 0, 0, 0}, {0, 0, 0, 0}};

    for (int cc = 0; cc < CDIM; cc += 64) {
        __syncthreads();
        #pragma unroll
        for (int it = 0; it < 2; ++it) {
            const int t  = tid + it * 256;
            const int r  = t >> 4;
            const int c4 = t & 15;
            const float4 v4 = *reinterpret_cast<const float4*>(
                &x[(row0 + r) * CDIM + cc + c4 * 4]);
            *reinterpret_cast<float4*>(&xs[r][c4 * 4]) = v4;
        }
        {
            const float4* wqg = reinterpret_cast<const float4*>(&Wq[(size_t)cc * HDIM]);
            const float4* wkg = reinterpret_cast<const float4*>(&Wk[(size_t)cc * HDIM]);
            const float4* wvg = reinterpret_cast<const float4*>(&Wv[(size_t)cc * HDIM]);
            float4* wql = reinterpret_cast<float4*>(wqs);
            float4* wkl = reinterpret_cast<float4*>(wks);
            float4* wvl = reinterpret_cast<float4*>(wvs);
            #pragma unroll
            for (int it = 0; it < 4; ++it) {
                const int t = tid + it * 256;
                wql[t] = wqg[t];
                wkl[t] = wkg[t];
                wvl[t] = wvg[t];
            }
        }
        __syncthreads();
        #pragma unroll 4
        for (int c = 0; c < 64; ++c) {
            const float4 wq4 = *reinterpret_cast<const float4*>(&wqs[c * 64 + tx * 4]);
            const float4 wk4 = *reinterpret_cast<const float4*>(&wks[c * 64 + tx * 4]);
            const float4 wv4 = *reinterpret_cast<const float4*>(&wvs[c * 64 + tx * 4]);
            #pragma unroll
            for (int i = 0; i < 2; ++i) {
                const float  xv = xs[ty * 2 + i][c];
                const double xd = (double)xv;
                qa[i][0] += xd * (double)wq4.x;
                qa[i][1] += xd * (double)wq4.y;
                qa[i][2] += xd * (double)wq4.z;
                qa[i][3] += xd * (double)wq4.w;
                ka[i][0] += xd * (double)wk4.x;
                ka[i][1] += xd * (double)wk4.y;
                ka[i][2] += xd * (double)wk4.z;
                ka[i][3] += xd * (double)wk4.w;
                va[i][0] += xv * wv4.x;
                va[i][1] += xv * wv4.y;
                va[i][2] += xv * wv4.z;
                va[i][3] += xv * wv4.w;
            }
        }
    }
    #pragma unroll
    for (int i = 0; i < 2; ++i) {
        const size_t row = row0 + ty * 2 + i;
        *reinterpret_cast<double2*>(&qd[row * HDIM + tx * 4])     = make_double2(qa[i][0], qa[i][1]);
        *reinterpret_cast<double2*>(&qd[row * HDIM + tx * 4 + 2]) = make_double2(qa[i][2], qa[i][3]);
        *reinterpret_cast<double2*>(&kd[row * HDIM + tx * 4])     = make_double2(ka[i][0], ka[i][1]);
        *reinterpret_cast<double2*>(&kd[row * HDIM + tx * 4 + 2]) = make_double2(ka[i][2], ka[i][3]);
        *reinterpret_cast<float4*>(&vf[row * HDIM + tx * 4]) =
            make_float4(va[i][0], va[i][1], va[i][2], va[i][3]);
    }
}

// ---------------------------------------------------------------- argmin engine
// grid (8, 64): blockIdx.x = BATCH with gridDim.x == 8 -> linear%8 == bx -> each
// XCD hosts exactly one batch; its 64 blocks share kd[b] (1 MB) in the 4 MB L2.
// CU-pair balance: blocks by and by+32 co-resident; tb = by<32? by : 95-by makes
// pair work ~constant. Score/capture/refinement logic = round-9 proven.
__global__ __launch_bounds__(256, 3) void argmin_kernel(
    const double* __restrict__ qd,
    const double* __restrict__ kd,
    const float*  __restrict__ vf,
    float* __restrict__ out)
{
    __shared__ float qf[QROWS][68];
    __shared__ float kf[2][64][68];
    __shared__ unsigned cnt[QROWS];
    __shared__ unsigned short cand[QROWS][CAP];

    const int tid = threadIdx.x;
    const int tx  = tid & 15;       // score cols 16j + tx (consecutive -> conflict-free)
    const int ty  = tid >> 4;       // score rows 2ty, 2ty+1
    const int b   = blockIdx.x;     // batch == XCD (gridDim.x = 8)
    const int byy = blockIdx.y;
    const int tb  = (byy < 32) ? byy : 95 - byy;   // co-CU pair work ~constant
    const int r0  = tb * QROWS;
    const int sb0 = tb >> 1;        // first s-block containing any future col

    // stage qf (fp64 -> fp32, coalesced)
    {
        const double* qsrc = qd + ((size_t)b * SEQ + r0) * HDIM;
        #pragma unroll
        for (int it = 0; it < 8; ++it) {
            const int idx = tid + it * 256;
            qf[idx >> 6][idx & 63] = (float)qsrc[(idx >> 6) * HDIM + (idx & 63)];
        }
    }
    if (tid < QROWS) cnt[tid] = 0;

    const int c2 = tid & 31;
    const int rb = tid >> 5;
    // stage kf[0] = tile sb0 (load -> immediate LDS write, transient regs only)
    {
        const double* ks = kd + ((size_t)b * SEQ + (size_t)sb0 * 64) * HDIM;
        #pragma unroll
        for (int it = 0; it < 8; ++it) {
            const int r = rb + it * 8;
            const double2 v2 = *reinterpret_cast<const double2*>(
                &ks[(size_t)r * HDIM + 2 * c2]);
            kf[0][r][2 * c2]     = (float)v2.x;
            kf[0][r][2 * c2 + 1] = (float)v2.y;
        }
    }
    __syncthreads();

    float mrun[2] = {3.0e38f, 3.0e38f};
    int cur = 0;

    for (int sb = sb0; sb < NSB; ++sb) {
        // stage next tile into the OTHER buffer (loads overlap compute below)
        if (sb + 1 < NSB) {
            const double* ks = kd + ((size_t)b * SEQ + (size_t)(sb + 1) * 64) * HDIM;
            #pragma unroll
            for (int it = 0; it < 8; ++it) {
                const int r = rb + it * 8;
                const double2 v2 = *reinterpret_cast<const double2*>(
                    &ks[(size_t)r * HDIM + 2 * c2]);
                kf[cur ^ 1][r][2 * c2]     = (float)v2.x;
                kf[cur ^ 1][r][2 * c2 + 1] = (float)v2.y;
            }
        }

        // ---- fp32 scores: s[i][j] = q[2ty+i] . k[16j+tx]
        float s[2][4] = {{0.f, 0.f, 0.f, 0.f}, {0.f, 0.f, 0.f, 0.f}};
        #pragma unroll
        for (int d4 = 0; d4 < 16; ++d4) {
            const float4 q0 = *reinterpret_cast<const float4*>(&qf[2 * ty][4 * d4]);
            const float4 q1 = *reinterpret_cast<const float4*>(&qf[2 * ty + 1][4 * d4]);
            #pragma unroll
            for (int j = 0; j < 4; ++j) {
                const float4 kv = *reinterpret_cast<const float4*>(&kf[cur][16 * j + tx][4 * d4]);
                s[0][j] += q0.x * kv.x + q0.y * kv.y + q0.z * kv.z + q0.w * kv.w;
                s[1][j] += q1.x * kv.x + q1.y * kv.y + q1.z * kv.z + q1.w * kv.w;
            }
        }

        // ---- future-only running min + candidate capture
        #pragma unroll
        for (int i = 0; i < 2; ++i) {
            const int rloc = 2 * ty + i;
            const int rg   = r0 + rloc;
            float sm[4];
            float tmin = 3.0e38f;
            #pragma unroll
            for (int j = 0; j < 4; ++j) {
                const int col = sb * 64 + 16 * j + tx;
                sm[j] = (col > rg) ? s[i][j] : 3.0e38f;   // FUTURE only
                tmin = fminf(tmin, sm[j]);
            }
            #pragma unroll
            for (int off = 8; off > 0; off >>= 1)
                tmin = fminf(tmin, __shfl_xor(tmin, off, 16));
            const float mnew = fminf(mrun[i], tmin);
            mrun[i] = mnew;
            const float thr = mnew + MARGIN;
            #pragma unroll
            for (int j = 0; j < 4; ++j) {
                if (sm[j] <= thr) {
                    const unsigned slot = atomicAdd(&cnt[rloc], 1u);
                    if (slot < CAP)
                        cand[rloc][slot] = (unsigned short)(sb * 64 + 16 * j + tx);
                }
            }
        }
        __syncthreads();   // kf[cur] reads + kf[cur^1] writes both complete
        cur ^= 1;
    }

    // ---- refinement: 8 lanes per row, exact fp64 dots on candidates
    const int row = tid >> 3, l8 = tid & 7;
    const int rg  = r0 + row;
    const unsigned n_raw = cnt[row];
    const int  n   = (n_raw < CAP) ? (int)n_raw : CAP;
    const bool ovf = n_raw > CAP;
    double min1 = 1.0e300, min2 = 1.0e300;
    int amin = -1;
    const double* qrow = qd + ((size_t)b * SEQ + rg) * HDIM;
    for (int c = 0; c < n; ++c) {
        const int col = cand[row][c];
        const double* krow = kd + ((size_t)b * SEQ + col) * HDIM;
        double part = 0.0;
        #pragma unroll
        for (int dd = 0; dd < 8; ++dd)
            part += qrow[8 * l8 + dd] * krow[8 * l8 + dd];
        #pragma unroll
        for (int off = 4; off > 0; off >>= 1)
            part += __shfl_xor(part, off, 8);
        if (part < min1) { min2 = min1; min1 = part; amin = col; }
        else if (part < min2) { min2 = part; }
    }
    // honest (no sufficiently-negative future / empty future), ambiguous tie,
    // or overflow -> exact-row fallback via NaN sentinel in out[rg][0].
    const bool flag = (n == 0) || ovf || (min1 > -1e-10) || ((min2 - min1) < 1e-11);
    float* orow = out + ((size_t)b * SEQ + rg) * HDIM;
    if (flag) {
        if (l8 == 0) orow[0] = __uint_as_float(SENTINEL);
    } else {
        const float* vrow = vf + ((size_t)b * SEQ + amin) * HDIM;
        const float4 v0 = *reinterpret_cast<const float4*>(&vrow[8 * l8]);
        const float4 v1 = *reinterpret_cast<const float4*>(&vrow[8 * l8 + 4]);
        *reinterpret_cast<float4*>(&orow[8 * l8])     = v0;
        *reinterpret_cast<float4*>(&orow[8 * l8 + 4]) = v1;
    }
}

// ---------------------------------------------------------------- exact-row fallback
// Full fp64 reference evaluation of flagged rows (expected ~2/batch).
// grid (8, 32): bx = batch (XCD-local kd), parallel flag prescan.
__global__ __launch_bounds__(256) void exact_kernel(
    const double* __restrict__ qd,
    const double* __restrict__ kd,
    const float*  __restrict__ vf,
    float* __restrict__ out)
{
    __shared__ double qrow[HDIM];
    __shared__ float  pbuf[SEQ];
    __shared__ float  outacc[4][HDIM];
    __shared__ double mred[4];
    __shared__ float  psred[4];
    __shared__ unsigned char fl[64];

    const int tid  = threadIdx.x;
    const int wid  = tid >> 6, lane = tid & 63;
    const int b    = blockIdx.x;
    const int r0   = blockIdx.y * 64;

    if (tid < 64) {
        const float v = out[((size_t)b * SEQ + r0 + tid) * HDIM];
        fl[tid] = (__float_as_uint(v) == SENTINEL) ? 1 : 0;
    }
    __syncthreads();

    for (int r = 0; r < 64; ++r) {
        if (!fl[r]) continue;                               // uniform (LDS)
        const int rg = r0 + r;
        float* orow = out + ((size_t)b * SEQ + rg) * HDIM;

        if (tid < HDIM) qrow[tid] = qd[((size_t)b * SEQ + rg) * HDIM + tid];
        __syncthreads();

        double lg[8];
        double mymax = -1.0e300;
        #pragma unroll
        for (int it = 0; it < 8; ++it) {
            const int col = tid + it * 256;
            const double* kr = kd + ((size_t)b * SEQ + col) * HDIM;
            double raw = 0.0;
            for (int d = 0; d < HDIM; ++d) raw += qrow[d] * kr[d];
            lg[it] = raw * ((col <= rg) ? 0.125 : MASKC);
            mymax = fmax(mymax, lg[it]);
        }
        #pragma unroll
        for (int off = 32; off > 0; off >>= 1)
            mymax = fmax(mymax, __shfl_xor(mymax, off, 64));
        if (lane == 0) mred[wid] = mymax;
        __syncthreads();
        const double M = fmax(fmax(mred[0], mred[1]), fmax(mred[2], mred[3]));

        float mypsum = 0.f;
        #pragma unroll
        for (int it = 0; it < 8; ++it) {
            const int col = tid + it * 256;
            const double dl = lg[it] - M;
            const float p = (dl < -80.0) ? 0.f : (float)exp(dl);
            pbuf[col] = p;
            mypsum += p;
        }
        #pragma unroll
        for (int off = 32; off > 0; off >>= 1)
            mypsum += __shfl_xor(mypsum, off, 64);
        if (lane == 0) psred[wid] = mypsum;
        __syncthreads();
        const float PS = psred[0] + psred[1] + psred[2] + psred[3];

        const int d = tid & 63, chunk = tid >> 6;
        float acc = 0.f;
        for (int cc = 0; cc < 512; ++cc) {
            const int col = chunk * 512 + cc;
            acc += pbuf[col] * vf[((size_t)b * SEQ + col) * HDIM + d];
        }
        outacc[chunk][d] = acc;
        __syncthreads();
        if (tid < HDIM)
            orow[tid] = (outacc[0][tid] + outacc[1][tid] +
                         outacc[2][tid] + outacc[3][tid]) / PS;
        __syncthreads();
    }
}

extern "C" void kernel_launch(void* const* d_in, const int* in_sizes, int n_in,
                              void* d_out, int out_size, void* d_ws, size_t ws_size,
                              hipStream_t stream)
{
    const float* x  = (const float*)d_in[0];
    const float* Wk = (const float*)d_in[1];
    const float* Wq = (const float*)d_in[2];
    const float* Wv = (const float*)d_in[3];
    float* out = (float*)d_out;

    // workspace: q fp64 (8 MB) | k fp64 (8 MB) | v fp32 (4 MB) — proven 20 MB layout
    double* qd = (double*)d_ws;
    double* kd = qd + (size_t)BATCH * SEQ * HDIM;
    float*  vf = (float*)(kd + (size_t)BATCH * SEQ * HDIM);

    qkv_proj_kernel<<<dim3(512), dim3(256), 0, stream>>>(x, Wk, Wq, Wv, qd, kd, vf);
    argmin_kernel<<<dim3(8, 64), dim3(256), 0, stream>>>(qd, kd, vf, out);
    exact_kernel<<<dim3(8, SEQ / 64), dim3(256), 0, stream>>>(qd, kd, vf, out);
}

// Round 11
// 1051.310 us; speedup vs baseline: 1.9159x; 1.4828x over previous
//
#include <hip/hip_runtime.h>
#include <math.h>

#define BATCH 8
#define SEQ   2048
#define CDIM  768
#define HDIM  64
#define QROWS 32
#define NSB   (SEQ / 64)
#define CAP   24
#define MARGIN 1e-2f
// exact: (raw * -1e14) * 0.125 == raw * (-1e14 * 0.125) (pow-2 scale commutes w/ rounding)
#define MASKC (-99999999999999.0 * 0.125)
#define SENTINEL 0x7FC0DEADu   // NaN payload: flags honest/ambiguous rows inside d_out

// ---------------------------------------------------------------- projection
// q,k fp64 (np-matching score ordering); v fp32.  (round-8/9/10 proven, unchanged)
__global__ __launch_bounds__(256) void qkv_proj_kernel(
    const float* __restrict__ x,
    const float* __restrict__ Wk,
    const float* __restrict__ Wq,
    const float* __restrict__ Wv,
    double* __restrict__ qd,
    double* __restrict__ kd,
    float*  __restrict__ vf)
{
    __shared__ float xs[32][68];
    __shared__ float wqs[64 * 64];
    __shared__ float wks[64 * 64];
    __shared__ float wvs[64 * 64];

    const int tid = threadIdx.x;
    const int tx  = tid & 15;
    const int ty  = tid >> 4;
    const size_t row0 = (size_t)blockIdx.x * 32;

    double qa[2][4] = {{0, 0, 0, 0}, {0, 0, 0, 0}};
    double ka[2][4] = {{0, 0, 0, 0}, {0, 0, 0, 0}};
    float  va[2][4] = {{0, 0, 0, 0}, {0, 0, 0, 0}};

    for (int cc = 0; cc < CDIM; cc += 64) {
        __syncthreads();
        #pragma unroll
        for (int it = 0; it < 2; ++it) {
            const int t  = tid + it * 256;
            const int r  = t >> 4;
            const int c4 = t & 15;
            const float4 v4 = *reinterpret_cast<const float4*>(
                &x[(row0 + r) * CDIM + cc + c4 * 4]);
            *reinterpret_cast<float4*>(&xs[r][c4 * 4]) = v4;
        }
        {
            const float4* wqg = reinterpret_cast<const float4*>(&Wq[(size_t)cc * HDIM]);
            const float4* wkg = reinterpret_cast<const float4*>(&Wk[(size_t)cc * HDIM]);
            const float4* wvg = reinterpret_cast<const float4*>(&Wv[(size_t)cc * HDIM]);
            float4* wql = reinterpret_cast<float4*>(wqs);
            float4* wkl = reinterpret_cast<float4*>(wks);
            float4* wvl = reinterpret_cast<float4*>(wvs);
            #pragma unroll
            for (int it = 0; it < 4; ++it) {
                const int t = tid + it * 256;
                wql[t] = wqg[t];
                wkl[t] = wkg[t];
                wvl[t] = wvg[t];
            }
        }
        __syncthreads();
        #pragma unroll 4
        for (int c = 0; c < 64; ++c) {
            const float4 wq4 = *reinterpret_cast<const float4*>(&wqs[c * 64 + tx * 4]);
            const float4 wk4 = *reinterpret_cast<const float4*>(&wks[c * 64 + tx * 4]);
            const float4 wv4 = *reinterpret_cast<const float4*>(&wvs[c * 64 + tx * 4]);
            #pragma unroll
            for (int i = 0; i < 2; ++i) {
                const float  xv = xs[ty * 2 + i][c];
                const double xd = (double)xv;
                qa[i][0] += xd * (double)wq4.x;
                qa[i][1] += xd * (double)wq4.y;
                qa[i][2] += xd * (double)wq4.z;
                qa[i][3] += xd * (double)wq4.w;
                ka[i][0] += xd * (double)wk4.x;
                ka[i][1] += xd * (double)wk4.y;
                ka[i][2] += xd * (double)wk4.z;
                ka[i][3] += xd * (double)wk4.w;
                va[i][0] += xv * wv4.x;
                va[i][1] += xv * wv4.y;
                va[i][2] += xv * wv4.z;
                va[i][3] += xv * wv4.w;
            }
        }
    }
    #pragma unroll
    for (int i = 0; i < 2; ++i) {
        const size_t row = row0 + ty * 2 + i;
        *reinterpret_cast<double2*>(&qd[row * HDIM + tx * 4])     = make_double2(qa[i][0], qa[i][1]);
        *reinterpret_cast<double2*>(&qd[row * HDIM + tx * 4 + 2]) = make_double2(qa[i][2], qa[i][3]);
        *reinterpret_cast<double2*>(&kd[row * HDIM + tx * 4])     = make_double2(ka[i][0], ka[i][1]);
        *reinterpret_cast<double2*>(&kd[row * HDIM + tx * 4 + 2]) = make_double2(ka[i][2], ka[i][3]);
        *reinterpret_cast<float4*>(&vf[row * HDIM + tx * 4]) =
            make_float4(va[i][0], va[i][1], va[i][2], va[i][3]);
    }
}

// ---------------------------------------------------------------- argmin engine
// Spill-proof hot loop: no atomics (ballot capture, register counts), no
// runtime-indexed buffers (static kfA/kfB ping-pong), no register arrays
// (named scalars). Logic identical to round-10-proven capture/refinement.
__device__ __forceinline__ void rowcap(
    float a0, float a1, float a2, float a3,
    int rloc, int rg, int sb, int tx, unsigned gsh,
    float& mrun, unsigned& cnt,
    unsigned short (*cand)[CAP])
{
    a0 = (sb * 64 + tx      > rg) ? a0 : 3.0e38f;   // FUTURE only
    a1 = (sb * 64 + 16 + tx > rg) ? a1 : 3.0e38f;
    a2 = (sb * 64 + 32 + tx > rg) ? a2 : 3.0e38f;
    a3 = (sb * 64 + 48 + tx > rg) ? a3 : 3.0e38f;
    float tmin = fminf(fminf(a0, a1), fminf(a2, a3));
    #pragma unroll
    for (int off = 8; off > 0; off >>= 1)
        tmin = fminf(tmin, __shfl_xor(tmin, off, 16));
    mrun = fminf(mrun, tmin);
    const float thr = mrun + MARGIN;
    #pragma unroll
    for (int j = 0; j < 4; ++j) {
        const float aj = (j == 0) ? a0 : (j == 1) ? a1 : (j == 2) ? a2 : a3;
        const bool pred = (aj <= thr);
        const unsigned long long bal = __ballot(pred ? 1 : 0);
        const unsigned m16 = (unsigned)((bal >> gsh) & 0xFFFFull);
        if (pred) {
            const unsigned slot = cnt + (unsigned)__popc(m16 & ((1u << tx) - 1u));
            if (slot < CAP)
                cand[rloc][slot] = (unsigned short)(sb * 64 + 16 * j + tx);
        }
        cnt += (unsigned)__popc(m16);
    }
}

#define STAGE(KF, SB)                                                          \
    { const double* ksrc = kd + ((size_t)b * SEQ + (size_t)(SB) * 64) * HDIM;  \
      _Pragma("unroll")                                                        \
      for (int it = 0; it < 8; ++it) {                                         \
          const int r = rb + it * 8;                                           \
          const double2 v2 = *reinterpret_cast<const double2*>(                \
              &ksrc[(size_t)r * HDIM + 2 * c2]);                               \
          KF[r][2 * c2]     = (float)v2.x;                                     \
          KF[r][2 * c2 + 1] = (float)v2.y; } }

#define BODY(KF, SB)                                                           \
    { float s00 = 0.f, s01 = 0.f, s02 = 0.f, s03 = 0.f;                        \
      float s10 = 0.f, s11 = 0.f, s12 = 0.f, s13 = 0.f;                        \
      _Pragma("unroll")                                                        \
      for (int d4 = 0; d4 < 16; ++d4) {                                        \
          const float4 q0 = *reinterpret_cast<const float4*>(&qf[2 * ty][4 * d4]);     \
          const float4 q1 = *reinterpret_cast<const float4*>(&qf[2 * ty + 1][4 * d4]); \
          const float4 k0 = *reinterpret_cast<const float4*>(&KF[tx][4 * d4]);         \
          const float4 k1 = *reinterpret_cast<const float4*>(&KF[16 + tx][4 * d4]);    \
          const float4 k2 = *reinterpret_cast<const float4*>(&KF[32 + tx][4 * d4]);    \
          const float4 k3 = *reinterpret_cast<const float4*>(&KF[48 + tx][4 * d4]);    \
          s00 += q0.x*k0.x + q0.y*k0.y + q0.z*k0.z + q0.w*k0.w;                \
          s01 += q0.x*k1.x + q0.y*k1.y + q0.z*k1.z + q0.w*k1.w;                \
          s02 += q0.x*k2.x + q0.y*k2.y + q0.z*k2.z + q0.w*k2.w;                \
          s03 += q0.x*k3.x + q0.y*k3.y + q0.z*k3.z + q0.w*k3.w;                \
          s10 += q1.x*k0.x + q1.y*k0.y + q1.z*k0.z + q1.w*k0.w;                \
          s11 += q1.x*k1.x + q1.y*k1.y + q1.z*k1.z + q1.w*k1.w;                \
          s12 += q1.x*k2.x + q1.y*k2.y + q1.z*k2.z + q1.w*k2.w;                \
          s13 += q1.x*k3.x + q1.y*k3.y + q1.z*k3.z + q1.w*k3.w;                \
      }                                                                        \
      rowcap(s00, s01, s02, s03, 2 * ty,     r0 + 2 * ty,     (SB), tx, gsh, mrun0, cnt0, cand); \
      rowcap(s10, s11, s12, s13, 2 * ty + 1, r0 + 2 * ty + 1, (SB), tx, gsh, mrun1, cnt1, cand); }

__global__ __launch_bounds__(256, 3) void argmin_kernel(
    const double* __restrict__ qd,
    const double* __restrict__ kd,
    const float*  __restrict__ vf,
    float* __restrict__ out)
{
    __shared__ float qf[QROWS][68];
    __shared__ float kfA[64][68];
    __shared__ float kfB[64][68];
    __shared__ unsigned short cand[QROWS][CAP];
    __shared__ unsigned cntLDS[QROWS];

    const int tid  = threadIdx.x;
    const int lane = tid & 63;
    const unsigned gsh = (unsigned)(lane & 48);   // 16-lane group base in ballot
    const int tx  = tid & 15;       // score cols 16j + tx (consecutive -> conflict-free)
    const int ty  = tid >> 4;       // score rows 2ty, 2ty+1
    const int b   = blockIdx.x;     // batch == XCD (gridDim.x = 8)
    const int byy = blockIdx.y;
    const int tb  = (byy < 32) ? byy : 95 - byy;   // co-CU pair work ~constant
    const int r0  = tb * QROWS;
    const int sb0 = tb >> 1;        // first s-block containing any future col

    // stage qf (fp64 -> fp32, coalesced)
    {
        const double* qsrc = qd + ((size_t)b * SEQ + r0) * HDIM;
        #pragma unroll
        for (int it = 0; it < 8; ++it) {
            const int idx = tid + it * 256;
            qf[idx >> 6][idx & 63] = (float)qsrc[(idx >> 6) * HDIM + (idx & 63)];
        }
    }

    const int c2 = tid & 31;
    const int rb = tid >> 5;

    float mrun0 = 3.0e38f, mrun1 = 3.0e38f;
    unsigned cnt0 = 0, cnt1 = 0;

    STAGE(kfA, sb0);
    __syncthreads();

    int sb = sb0;
    while (true) {
        if (sb + 1 < NSB) STAGE(kfB, sb + 1);
        BODY(kfA, sb);
        __syncthreads();
        ++sb;
        if (sb >= NSB) break;
        if (sb + 1 < NSB) STAGE(kfA, sb + 1);
        BODY(kfB, sb);
        __syncthreads();
        ++sb;
        if (sb >= NSB) break;
    }

    if (tx == 0) {
        cntLDS[2 * ty]     = cnt0;
        cntLDS[2 * ty + 1] = cnt1;
    }
    __syncthreads();

    // ---- refinement: 8 lanes per row, exact fp64 dots on candidates
    const int row = tid >> 3, l8 = tid & 7;
    const int rg  = r0 + row;
    const unsigned n_raw = cntLDS[row];
    const int  n   = (n_raw < CAP) ? (int)n_raw : CAP;
    const bool ovf = n_raw > CAP;
    double min1 = 1.0e300, min2 = 1.0e300;
    int amin = -1;
    const double* qrow = qd + ((size_t)b * SEQ + rg) * HDIM;
    for (int c = 0; c < n; ++c) {
        const int col = cand[row][c];
        const double* krow = kd + ((size_t)b * SEQ + col) * HDIM;
        double part = 0.0;
        #pragma unroll
        for (int dd = 0; dd < 8; ++dd)
            part += qrow[8 * l8 + dd] * krow[8 * l8 + dd];
        #pragma unroll
        for (int off = 4; off > 0; off >>= 1)
            part += __shfl_xor(part, off, 8);
        if (part < min1) { min2 = min1; min1 = part; amin = col; }
        else if (part < min2) { min2 = part; }
    }
    // honest (no sufficiently-negative future / empty future), ambiguous tie,
    // or overflow -> exact-row fallback via NaN sentinel in out[rg][0].
    const bool flag = (n == 0) || ovf || (min1 > -1e-10) || ((min2 - min1) < 1e-11);
    float* orow = out + ((size_t)b * SEQ + rg) * HDIM;
    if (flag) {
        if (l8 == 0) orow[0] = __uint_as_float(SENTINEL);
    } else {
        const float* vrow = vf + ((size_t)b * SEQ + amin) * HDIM;
        const float4 v0 = *reinterpret_cast<const float4*>(&vrow[8 * l8]);
        const float4 v1 = *reinterpret_cast<const float4*>(&vrow[8 * l8 + 4]);
        *reinterpret_cast<float4*>(&orow[8 * l8])     = v0;
        *reinterpret_cast<float4*>(&orow[8 * l8 + 4]) = v1;
    }
}

// ---------------------------------------------------------------- exact-row fallback
// Full fp64 reference evaluation of flagged rows (expected ~2/batch).
__global__ __launch_bounds__(256) void exact_kernel(
    const double* __restrict__ qd,
    const double* __restrict__ kd,
    const float*  __restrict__ vf,
    float* __restrict__ out)
{
    __shared__ double qrow[HDIM];
    __shared__ float  pbuf[SEQ];
    __shared__ float  outacc[4][HDIM];
    __shared__ double mred[4];
    __shared__ float  psred[4];
    __shared__ unsigned char fl[64];

    const int tid  = threadIdx.x;
    const int wid  = tid >> 6, lane = tid & 63;
    const int b    = blockIdx.x;
    const int r0   = blockIdx.y * 64;

    if (tid < 64) {
        const float v = out[((size_t)b * SEQ + r0 + tid) * HDIM];
        fl[tid] = (__float_as_uint(v) == SENTINEL) ? 1 : 0;
    }
    __syncthreads();

    for (int r = 0; r < 64; ++r) {
        if (!fl[r]) continue;                               // uniform (LDS)
        const int rg = r0 + r;
        float* orow = out + ((size_t)b * SEQ + rg) * HDIM;

        if (tid < HDIM) qrow[tid] = qd[((size_t)b * SEQ + rg) * HDIM + tid];
        __syncthreads();

        double lg[8];
        double mymax = -1.0e300;
        #pragma unroll
        for (int it = 0; it < 8; ++it) {
            const int col = tid + it * 256;
            const double* kr = kd + ((size_t)b * SEQ + col) * HDIM;
            double raw = 0.0;
            for (int d = 0; d < HDIM; ++d) raw += qrow[d] * kr[d];
            lg[it] = raw * ((col <= rg) ? 0.125 : MASKC);
            mymax = fmax(mymax, lg[it]);
        }
        #pragma unroll
        for (int off = 32; off > 0; off >>= 1)
            mymax = fmax(mymax, __shfl_xor(mymax, off, 64));
        if (lane == 0) mred[wid] = mymax;
        __syncthreads();
        const double M = fmax(fmax(mred[0], mred[1]), fmax(mred[2], mred[3]));

        float mypsum = 0.f;
        #pragma unroll
        for (int it = 0; it < 8; ++it) {
            const int col = tid + it * 256;
            const double dl = lg[it] - M;
            const float p = (dl < -80.0) ? 0.f : (float)exp(dl);
            pbuf[col] = p;
            mypsum += p;
        }
        #pragma unroll
        for (int off = 32; off > 0; off >>= 1)
            mypsum += __shfl_xor(mypsum, off, 64);
        if (lane == 0) psred[wid] = mypsum;
        __syncthreads();
        const float PS = psred[0] + psred[1] + psred[2] + psred[3];

        const int d = tid & 63, chunk = tid >> 6;
        float acc = 0.f;
        for (int cc = 0; cc < 512; ++cc) {
            const int col = chunk * 512 + cc;
            acc += pbuf[col] * vf[((size_t)b * SEQ + col) * HDIM + d];
        }
        outacc[chunk][d] = acc;
        __syncthreads();
        if (tid < HDIM)
            orow[tid] = (outacc[0][tid] + outacc[1][tid] +
                         outacc[2][tid] + outacc[3][tid]) / PS;
        __syncthreads();
    }
}

extern "C" void kernel_launch(void* const* d_in, const int* in_sizes, int n_in,
                              void* d_out, int out_size, void* d_ws, size_t ws_size,
                              hipStream_t stream)
{
    const float* x  = (const float*)d_in[0];
    const float* Wk = (const float*)d_in[1];
    const float* Wq = (const float*)d_in[2];
    const float* Wv = (const float*)d_in[3];
    float* out = (float*)d_out;

    // workspace: q fp64 (8 MB) | k fp64 (8 MB) | v fp32 (4 MB) — proven 20 MB layout
    double* qd = (double*)d_ws;
    double* kd = qd + (size_t)BATCH * SEQ * HDIM;
    float*  vf = (float*)(kd + (size_t)BATCH * SEQ * HDIM);

    qkv_proj_kernel<<<dim3(512), dim3(256), 0, stream>>>(x, Wk, Wq, Wv, qd, kd, vf);
    argmin_kernel<<<dim3(8, 64), dim3(256), 0, stream>>>(qd, kd, vf, out);
    exact_kernel<<<dim3(8, SEQ / 64), dim3(256), 0, stream>>>(qd, kd, vf, out);
}

// Round 13
// 412.126 us; speedup vs baseline: 4.8873x; 2.5509x over previous
//
#include <hip/hip_runtime.h>
#include <math.h>

#define BATCH 8
#define SEQ   2048
#define CDIM  768
#define HDIM  64
#define QROWS 32
#define NSB   (SEQ / 64)
#define MARGIN 1e-2f
// exact: (raw * -1e14) * 0.125 == raw * (-1e14 * 0.125) (pow-2 scale commutes w/ rounding)
#define MASKC (-99999999999999.0 * 0.125)
#define SENTINEL 0x7FC0DEADu   // NaN payload: flags honest/ambiguous rows inside d_out

// ---------------------------------------------------------------- projection
// q,k fp64 (np-matching score ordering); v fp32.  (round-8..11 proven, unchanged)
__global__ __launch_bounds__(256) void qkv_proj_kernel(
    const float* __restrict__ x,
    const float* __restrict__ Wk,
    const float* __restrict__ Wq,
    const float* __restrict__ Wv,
    double* __restrict__ qd,
    double* __restrict__ kd,
    float*  __restrict__ vf)
{
    __shared__ float xs[32][68];
    __shared__ float wqs[64 * 64];
    __shared__ float wks[64 * 64];
    __shared__ float wvs[64 * 64];

    const int tid = threadIdx.x;
    const int tx  = tid & 15;
    const int ty  = tid >> 4;
    const size_t row0 = (size_t)blockIdx.x * 32;

    double qa[2][4] = {{0, 0, 0, 0}, {0, 0, 0, 0}};
    double ka[2][4] = {{0, 0, 0, 0}, {0, 0, 0, 0}};
    float  va[2][4] = {{0, 0, 0, 0}, {0, 0, 0, 0}};

    for (int cc = 0; cc < CDIM; cc += 64) {
        __syncthreads();
        #pragma unroll
        for (int it = 0; it < 2; ++it) {
            const int t  = tid + it * 256;
            const int r  = t >> 4;
            const int c4 = t & 15;
            const float4 v4 = *reinterpret_cast<const float4*>(
                &x[(row0 + r) * CDIM + cc + c4 * 4]);
            *reinterpret_cast<float4*>(&xs[r][c4 * 4]) = v4;
        }
        {
            const float4* wqg = reinterpret_cast<const float4*>(&Wq[(size_t)cc * HDIM]);
            const float4* wkg = reinterpret_cast<const float4*>(&Wk[(size_t)cc * HDIM]);
            const float4* wvg = reinterpret_cast<const float4*>(&Wv[(size_t)cc * HDIM]);
            float4* wql = reinterpret_cast<float4*>(wqs);
            float4* wkl = reinterpret_cast<float4*>(wks);
            float4* wvl = reinterpret_cast<float4*>(wvs);
            #pragma unroll
            for (int it = 0; it < 4; ++it) {
                const int t = tid + it * 256;
                wql[t] = wqg[t];
                wkl[t] = wkg[t];
                wvl[t] = wvg[t];
            }
        }
        __syncthreads();
        #pragma unroll 4
        for (int c = 0; c < 64; ++c) {
            const float4 wq4 = *reinterpret_cast<const float4*>(&wqs[c * 64 + tx * 4]);
            const float4 wk4 = *reinterpret_cast<const float4*>(&wks[c * 64 + tx * 4]);
            const float4 wv4 = *reinterpret_cast<const float4*>(&wvs[c * 64 + tx * 4]);
            #pragma unroll
            for (int i = 0; i < 2; ++i) {
                const float  xv = xs[ty * 2 + i][c];
                const double xd = (double)xv;
                qa[i][0] += xd * (double)wq4.x;
                qa[i][1] += xd * (double)wq4.y;
                qa[i][2] += xd * (double)wq4.z;
                qa[i][3] += xd * (double)wq4.w;
                ka[i][0] += xd * (double)wk4.x;
                ka[i][1] += xd * (double)wk4.y;
                ka[i][2] += xd * (double)wk4.z;
                ka[i][3] += xd * (double)wk4.w;
                va[i][0] += xv * wv4.x;
                va[i][1] += xv * wv4.y;
                va[i][2] += xv * wv4.z;
                va[i][3] += xv * wv4.w;
            }
        }
    }
    #pragma unroll
    for (int i = 0; i < 2; ++i) {
        const size_t row = row0 + ty * 2 + i;
        *reinterpret_cast<double2*>(&qd[row * HDIM + tx * 4])     = make_double2(qa[i][0], qa[i][1]);
        *reinterpret_cast<double2*>(&qd[row * HDIM + tx * 4 + 2]) = make_double2(qa[i][2], qa[i][3]);
        *reinterpret_cast<double2*>(&kd[row * HDIM + tx * 4])     = make_double2(ka[i][0], ka[i][1]);
        *reinterpret_cast<double2*>(&kd[row * HDIM + tx * 4 + 2]) = make_double2(ka[i][2], ka[i][3]);
        *reinterpret_cast<float4*>(&vf[row * HDIM + tx * 4]) =
            make_float4(va[i][0], va[i][1], va[i][2], va[i][3]);
    }
}

// ---------------------------------------------------------------- argmin engine
// Capture = per-(row, sb) 64-bit ballot mask. ROUND-12 BUG: when a row's first
// tile had NO future cols, thr saturated to 3e38 and the masked sentinels
// (3e38) ballot'd TRUE -> past cols entered the candidate set -> wrong argmin.
// Fix: sentinel guard in the ballot + past-col skip in refinement.
__device__ __forceinline__ unsigned long long rowcap_mask(
    float a0, float a1, float a2, float a3,
    int rg, int sb, int tx, unsigned gsh, float& mrun)
{
    a0 = (sb * 64 + tx      > rg) ? a0 : 3.0e38f;   // FUTURE only
    a1 = (sb * 64 + 16 + tx > rg) ? a1 : 3.0e38f;
    a2 = (sb * 64 + 32 + tx > rg) ? a2 : 3.0e38f;
    a3 = (sb * 64 + 48 + tx > rg) ? a3 : 3.0e38f;
    float tmin = fminf(fminf(a0, a1), fminf(a2, a3));
    #pragma unroll
    for (int off = 8; off > 0; off >>= 1)
        tmin = fminf(tmin, __shfl_xor(tmin, off, 16));
    mrun = fminf(mrun, tmin);
    const float thr = mrun + MARGIN;
    // sentinel guard: masked entries (3e38) must never be captured, even when
    // thr itself saturates to 3e38 (row with no future cols seen yet).
    const unsigned long long b0 = __ballot((a0 <= thr) && (a0 < 3.0e37f));
    const unsigned long long b1 = __ballot((a1 <= thr) && (a1 < 3.0e37f));
    const unsigned long long b2 = __ballot((a2 <= thr) && (a2 < 3.0e37f));
    const unsigned long long b3 = __ballot((a3 <= thr) && (a3 < 3.0e37f));
    return ((b0 >> gsh) & 0xFFFFull)
         | (((b1 >> gsh) & 0xFFFFull) << 16)
         | (((b2 >> gsh) & 0xFFFFull) << 32)
         | (((b3 >> gsh) & 0xFFFFull) << 48);
}

#define STAGE(KF, SB)                                                          \
    { const double* ksrc = kd + ((size_t)b * SEQ + (size_t)(SB) * 64) * HDIM;  \
      _Pragma("unroll")                                                        \
      for (int it = 0; it < 8; ++it) {                                         \
          const int r = rb + it * 8;                                           \
          const double2 v2 = *reinterpret_cast<const double2*>(                \
              &ksrc[(size_t)r * HDIM + 2 * c2]);                               \
          KF[r][2 * c2]     = (float)v2.x;                                     \
          KF[r][2 * c2 + 1] = (float)v2.y; } }

#define BODY(KF, SB)                                                           \
    { float s00 = 0.f, s01 = 0.f, s02 = 0.f, s03 = 0.f;                        \
      float s10 = 0.f, s11 = 0.f, s12 = 0.f, s13 = 0.f;                        \
      _Pragma("unroll")                                                        \
      for (int d4 = 0; d4 < 16; ++d4) {                                        \
          const float4 q0 = *reinterpret_cast<const float4*>(&qf[2 * ty][4 * d4]);     \
          const float4 q1 = *reinterpret_cast<const float4*>(&qf[2 * ty + 1][4 * d4]); \
          const float4 k0 = *reinterpret_cast<const float4*>(&KF[tx][4 * d4]);         \
          const float4 k1 = *reinterpret_cast<const float4*>(&KF[16 + tx][4 * d4]);    \
          const float4 k2 = *reinterpret_cast<const float4*>(&KF[32 + tx][4 * d4]);    \
          const float4 k3 = *reinterpret_cast<const float4*>(&KF[48 + tx][4 * d4]);    \
          s00 += q0.x*k0.x + q0.y*k0.y + q0.z*k0.z + q0.w*k0.w;                \
          s01 += q0.x*k1.x + q0.y*k1.y + q0.z*k1.z + q0.w*k1.w;                \
          s02 += q0.x*k2.x + q0.y*k2.y + q0.z*k2.z + q0.w*k2.w;                \
          s03 += q0.x*k3.x + q0.y*k3.y + q0.z*k3.z + q0.w*k3.w;                \
          s10 += q1.x*k0.x + q1.y*k0.y + q1.z*k0.z + q1.w*k0.w;                \
          s11 += q1.x*k1.x + q1.y*k1.y + q1.z*k1.z + q1.w*k1.w;                \
          s12 += q1.x*k2.x + q1.y*k2.y + q1.z*k2.z + q1.w*k2.w;                \
          s13 += q1.x*k3.x + q1.y*k3.y + q1.z*k3.z + q1.w*k3.w;                \
      }                                                                        \
      const unsigned long long m0 =                                            \
          rowcap_mask(s00, s01, s02, s03, r0 + 2 * ty,     (SB), tx, gsh, mrun0); \
      const unsigned long long m1 =                                            \
          rowcap_mask(s10, s11, s12, s13, r0 + 2 * ty + 1, (SB), tx, gsh, mrun1); \
      if (tx == 0) {                                                           \
          candmask[2 * ty][(SB)]     = m0;                                     \
          candmask[2 * ty + 1][(SB)] = m1; } }

__global__ __launch_bounds__(256) void argmin_kernel(
    const double* __restrict__ qd,
    const double* __restrict__ kd,
    const float*  __restrict__ vf,
    float* __restrict__ out)
{
    __shared__ float qf[QROWS][68];
    __shared__ float kfA[64][68];
    __shared__ float kfB[64][68];
    __shared__ unsigned long long candmask[QROWS][NSB];

    const int tid  = threadIdx.x;
    const int lane = tid & 63;
    const unsigned gsh = (unsigned)(lane & 48);   // 16-lane group base in ballot
    const int tx  = tid & 15;       // score cols 16j + tx (consecutive -> conflict-free)
    const int ty  = tid >> 4;       // score rows 2ty, 2ty+1
    const int b   = blockIdx.x;     // batch == XCD (gridDim.x = 8)
    const int byy = blockIdx.y;
    const int tb  = (byy < 32) ? byy : 95 - byy;   // co-CU pair work ~constant
    const int r0  = tb * QROWS;
    const int sb0 = tb >> 1;        // first s-block containing any future col

    // stage qf (fp64 -> fp32, coalesced)
    {
        const double* qsrc = qd + ((size_t)b * SEQ + r0) * HDIM;
        #pragma unroll
        for (int it = 0; it < 8; ++it) {
            const int idx = tid + it * 256;
            qf[idx >> 6][idx & 63] = (float)qsrc[(idx >> 6) * HDIM + (idx & 63)];
        }
    }

    const int c2 = tid & 31;
    const int rb = tid >> 5;

    float mrun0 = 3.0e38f, mrun1 = 3.0e38f;

    STAGE(kfA, sb0);
    __syncthreads();

    int sb = sb0;
    while (true) {
        if (sb + 1 < NSB) STAGE(kfB, sb + 1);
        BODY(kfA, sb);
        __syncthreads();
        ++sb;
        if (sb >= NSB) break;
        if (sb + 1 < NSB) STAGE(kfA, sb + 1);
        BODY(kfB, sb);
        __syncthreads();
        ++sb;
        if (sb >= NSB) break;
    }
    __syncthreads();

    // ---- refinement: 8 lanes per row walk the bitmasks, exact fp64 dots
    const int row = tid >> 3, l8 = tid & 7;
    const int rg  = r0 + row;
    int n = 0;
    double min1 = 1.0e300, min2 = 1.0e300;
    int amin = -1;
    const double* qrow = qd + ((size_t)b * SEQ + rg) * HDIM;
    for (int sbi = sb0; sbi < NSB; ++sbi) {
        unsigned long long m = candmask[row][sbi];
        while (m) {
            const int p = __ffsll((long long)m) - 1;
            m &= m - 1;
            const int col = sbi * 64 + p;
            if (col <= rg) continue;          // defense in depth: FUTURE only
            ++n;
            const double* krow = kd + ((size_t)b * SEQ + col) * HDIM;
            double part = 0.0;
            #pragma unroll
            for (int dd = 0; dd < 8; ++dd)
                part += qrow[8 * l8 + dd] * krow[8 * l8 + dd];
            #pragma unroll
            for (int off = 4; off > 0; off >>= 1)
                part += __shfl_xor(part, off, 8);
            if (part < min1) { min2 = min1; min1 = part; amin = col; }
            else if (part < min2) { min2 = part; }
        }
    }
    // honest (no sufficiently-negative future / empty future) or ambiguous tie
    // -> exact-row fallback via NaN sentinel in out[rg][0].
    const bool flag = (n == 0) || (min1 > -1e-10) || ((min2 - min1) < 1e-11);
    float* orow = out + ((size_t)b * SEQ + rg) * HDIM;
    if (flag) {
        if (l8 == 0) orow[0] = __uint_as_float(SENTINEL);
    } else {
        const float* vrow = vf + ((size_t)b * SEQ + amin) * HDIM;
        const float4 v0 = *reinterpret_cast<const float4*>(&vrow[8 * l8]);
        const float4 v1 = *reinterpret_cast<const float4*>(&vrow[8 * l8 + 4]);
        *reinterpret_cast<float4*>(&orow[8 * l8])     = v0;
        *reinterpret_cast<float4*>(&orow[8 * l8 + 4]) = v1;
    }
}

// ---------------------------------------------------------------- exact-row fallback
// Full fp64 reference evaluation of flagged rows (expected ~2/batch).
__global__ __launch_bounds__(256) void exact_kernel(
    const double* __restrict__ qd,
    const double* __restrict__ kd,
    const float*  __restrict__ vf,
    float* __restrict__ out)
{
    __shared__ double qrow[HDIM];
    __shared__ float  pbuf[SEQ];
    __shared__ float  outacc[4][HDIM];
    __shared__ double mred[4];
    __shared__ float  psred[4];
    __shared__ unsigned char fl[64];

    const int tid  = threadIdx.x;
    const int wid  = tid >> 6, lane = tid & 63;
    const int b    = blockIdx.x;
    const int r0   = blockIdx.y * 64;

    if (tid < 64) {
        const float v = out[((size_t)b * SEQ + r0 + tid) * HDIM];
        fl[tid] = (__float_as_uint(v) == SENTINEL) ? 1 : 0;
    }
    __syncthreads();

    for (int r = 0; r < 64; ++r) {
        if (!fl[r]) continue;                               // uniform (LDS)
        const int rg = r0 + r;
        float* orow = out + ((size_t)b * SEQ + rg) * HDIM;

        if (tid < HDIM) qrow[tid] = qd[((size_t)b * SEQ + rg) * HDIM + tid];
        __syncthreads();

        double lg[8];
        double mymax = -1.0e300;
        #pragma unroll
        for (int it = 0; it < 8; ++it) {
            const int col = tid + it * 256;
            const double* kr = kd + ((size_t)b * SEQ + col) * HDIM;
            double raw = 0.0;
            for (int d = 0; d < HDIM; ++d) raw += qrow[d] * kr[d];
            lg[it] = raw * ((col <= rg) ? 0.125 : MASKC);
            mymax = fmax(mymax, lg[it]);
        }
        #pragma unroll
        for (int off = 32; off > 0; off >>= 1)
            mymax = fmax(mymax, __shfl_xor(mymax, off, 64));
        if (lane == 0) mred[wid] = mymax;
        __syncthreads();
        const double M = fmax(fmax(mred[0], mred[1]), fmax(mred[2], mred[3]));

        float mypsum = 0.f;
        #pragma unroll
        for (int it = 0; it < 8; ++it) {
            const int col = tid + it * 256;
            const double dl = lg[it] - M;
            const float p = (dl < -80.0) ? 0.f : (float)exp(dl);
            pbuf[col] = p;
            mypsum += p;
        }
        #pragma unroll
        for (int off = 32; off > 0; off >>= 1)
            mypsum += __shfl_xor(mypsum, off, 64);
        if (lane == 0) psred[wid] = mypsum;
        __syncthreads();
        const float PS = psred[0] + psred[1] + psred[2] + psred[3];

        const int d = tid & 63, chunk = tid >> 6;
        float acc = 0.f;
        for (int cc = 0; cc < 512; ++cc) {
            const int col = chunk * 512 + cc;
            acc += pbuf[col] * vf[((size_t)b * SEQ + col) * HDIM + d];
        }
        outacc[chunk][d] = acc;
        __syncthreads();
        if (tid < HDIM)
            orow[tid] = (outacc[0][tid] + outacc[1][tid] +
                         outacc[2][tid] + outacc[3][tid]) / PS;
        __syncthreads();
    }
}

extern "C" void kernel_launch(void* const* d_in, const int* in_sizes, int n_in,
                              void* d_out, int out_size, void* d_ws, size_t ws_size,
                              hipStream_t stream)
{
    const float* x  = (const float*)d_in[0];
    const float* Wk = (const float*)d_in[1];
    const float* Wq = (const float*)d_in[2];
    const float* Wv = (const float*)d_in[3];
    float* out = (float*)d_out;

    // workspace: q fp64 (8 MB) | k fp64 (8 MB) | v fp32 (4 MB) — proven 20 MB layout
    double* qd = (double*)d_ws;
    double* kd = qd + (size_t)BATCH * SEQ * HDIM;
    float*  vf = (float*)(kd + (size_t)BATCH * SEQ * HDIM);

    qkv_proj_kernel<<<dim3(512), dim3(256), 0, stream>>>(x, Wk, Wq, Wv, qd, kd, vf);
    argmin_kernel<<<dim3(8, 64), dim3(256), 0, stream>>>(qd, kd, vf, out);
    exact_kernel<<<dim3(8, SEQ / 64), dim3(256), 0, stream>>>(qd, kd, vf, out);
}

// Round 14
// 321.938 us; speedup vs baseline: 6.2565x; 1.2801x over previous
//
#include <hip/hip_runtime.h>
#include <math.h>

#define BATCH 8
#define SEQ   2048
#define CDIM  768
#define HDIM  64
#define QROWS 32
#define NSB   (SEQ / 64)
#define MARGIN 1e-2f
// exact: (raw * -1e14) * 0.125 == raw * (-1e14 * 0.125) (pow-2 scale commutes w/ rounding)
#define MASKC (-99999999999999.0 * 0.125)
#define SENTINEL 0x7FC0DEADu   // NaN payload: flags honest/ambiguous rows inside d_out

// ---------------------------------------------------------------- projection
// q,k fp64 (np-matching score ordering); v fp32.  (round-13 proven, unchanged)
__global__ __launch_bounds__(256) void qkv_proj_kernel(
    const float* __restrict__ x,
    const float* __restrict__ Wk,
    const float* __restrict__ Wq,
    const float* __restrict__ Wv,
    double* __restrict__ qd,
    double* __restrict__ kd,
    float*  __restrict__ vf)
{
    __shared__ float xs[32][68];
    __shared__ float wqs[64 * 64];
    __shared__ float wks[64 * 64];
    __shared__ float wvs[64 * 64];

    const int tid = threadIdx.x;
    const int tx  = tid & 15;
    const int ty  = tid >> 4;
    const size_t row0 = (size_t)blockIdx.x * 32;

    double qa[2][4] = {{0, 0, 0, 0}, {0, 0, 0, 0}};
    double ka[2][4] = {{0, 0, 0, 0}, {0, 0, 0, 0}};
    float  va[2][4] = {{0, 0, 0, 0}, {0, 0, 0, 0}};

    for (int cc = 0; cc < CDIM; cc += 64) {
        __syncthreads();
        #pragma unroll
        for (int it = 0; it < 2; ++it) {
            const int t  = tid + it * 256;
            const int r  = t >> 4;
            const int c4 = t & 15;
            const float4 v4 = *reinterpret_cast<const float4*>(
                &x[(row0 + r) * CDIM + cc + c4 * 4]);
            *reinterpret_cast<float4*>(&xs[r][c4 * 4]) = v4;
        }
        {
            const float4* wqg = reinterpret_cast<const float4*>(&Wq[(size_t)cc * HDIM]);
            const float4* wkg = reinterpret_cast<const float4*>(&Wk[(size_t)cc * HDIM]);
            const float4* wvg = reinterpret_cast<const float4*>(&Wv[(size_t)cc * HDIM]);
            float4* wql = reinterpret_cast<float4*>(wqs);
            float4* wkl = reinterpret_cast<float4*>(wks);
            float4* wvl = reinterpret_cast<float4*>(wvs);
            #pragma unroll
            for (int it = 0; it < 4; ++it) {
                const int t = tid + it * 256;
                wql[t] = wqg[t];
                wkl[t] = wkg[t];
                wvl[t] = wvg[t];
            }
        }
        __syncthreads();
        #pragma unroll 4
        for (int c = 0; c < 64; ++c) {
            const float4 wq4 = *reinterpret_cast<const float4*>(&wqs[c * 64 + tx * 4]);
            const float4 wk4 = *reinterpret_cast<const float4*>(&wks[c * 64 + tx * 4]);
            const float4 wv4 = *reinterpret_cast<const float4*>(&wvs[c * 64 + tx * 4]);
            #pragma unroll
            for (int i = 0; i < 2; ++i) {
                const float  xv = xs[ty * 2 + i][c];
                const double xd = (double)xv;
                qa[i][0] += xd * (double)wq4.x;
                qa[i][1] += xd * (double)wq4.y;
                qa[i][2] += xd * (double)wq4.z;
                qa[i][3] += xd * (double)wq4.w;
                ka[i][0] += xd * (double)wk4.x;
                ka[i][1] += xd * (double)wk4.y;
                ka[i][2] += xd * (double)wk4.z;
                ka[i][3] += xd * (double)wk4.w;
                va[i][0] += xv * wv4.x;
                va[i][1] += xv * wv4.y;
                va[i][2] += xv * wv4.z;
                va[i][3] += xv * wv4.w;
            }
        }
    }
    #pragma unroll
    for (int i = 0; i < 2; ++i) {
        const size_t row = row0 + ty * 2 + i;
        *reinterpret_cast<double2*>(&qd[row * HDIM + tx * 4])     = make_double2(qa[i][0], qa[i][1]);
        *reinterpret_cast<double2*>(&qd[row * HDIM + tx * 4 + 2]) = make_double2(qa[i][2], qa[i][3]);
        *reinterpret_cast<double2*>(&kd[row * HDIM + tx * 4])     = make_double2(ka[i][0], ka[i][1]);
        *reinterpret_cast<double2*>(&kd[row * HDIM + tx * 4 + 2]) = make_double2(ka[i][2], ka[i][3]);
        *reinterpret_cast<float4*>(&vf[row * HDIM + tx * 4]) =
            make_float4(va[i][0], va[i][1], va[i][2], va[i][3]);
    }
}

// ---------------------------------------------------------------- argmin engine
// (round-13 proven, unchanged) Capture = per-(row, sb) 64-bit ballot mask with
// sentinel guard; no occupancy cap (caps caused the GB-scale spill of r8-r11).
__device__ __forceinline__ unsigned long long rowcap_mask(
    float a0, float a1, float a2, float a3,
    int rg, int sb, int tx, unsigned gsh, float& mrun)
{
    a0 = (sb * 64 + tx      > rg) ? a0 : 3.0e38f;   // FUTURE only
    a1 = (sb * 64 + 16 + tx > rg) ? a1 : 3.0e38f;
    a2 = (sb * 64 + 32 + tx > rg) ? a2 : 3.0e38f;
    a3 = (sb * 64 + 48 + tx > rg) ? a3 : 3.0e38f;
    float tmin = fminf(fminf(a0, a1), fminf(a2, a3));
    #pragma unroll
    for (int off = 8; off > 0; off >>= 1)
        tmin = fminf(tmin, __shfl_xor(tmin, off, 16));
    mrun = fminf(mrun, tmin);
    const float thr = mrun + MARGIN;
    // sentinel guard: masked entries (3e38) must never be captured, even when
    // thr itself saturates to 3e38 (row with no future cols seen yet).
    const unsigned long long b0 = __ballot((a0 <= thr) && (a0 < 3.0e37f));
    const unsigned long long b1 = __ballot((a1 <= thr) && (a1 < 3.0e37f));
    const unsigned long long b2 = __ballot((a2 <= thr) && (a2 < 3.0e37f));
    const unsigned long long b3 = __ballot((a3 <= thr) && (a3 < 3.0e37f));
    return ((b0 >> gsh) & 0xFFFFull)
         | (((b1 >> gsh) & 0xFFFFull) << 16)
         | (((b2 >> gsh) & 0xFFFFull) << 32)
         | (((b3 >> gsh) & 0xFFFFull) << 48);
}

#define STAGE(KF, SB)                                                          \
    { const double* ksrc = kd + ((size_t)b * SEQ + (size_t)(SB) * 64) * HDIM;  \
      _Pragma("unroll")                                                        \
      for (int it = 0; it < 8; ++it) {                                         \
          const int r = rb + it * 8;                                           \
          const double2 v2 = *reinterpret_cast<const double2*>(                \
              &ksrc[(size_t)r * HDIM + 2 * c2]);                               \
          KF[r][2 * c2]     = (float)v2.x;                                     \
          KF[r][2 * c2 + 1] = (float)v2.y; } }

#define BODY(KF, SB)                                                           \
    { float s00 = 0.f, s01 = 0.f, s02 = 0.f, s03 = 0.f;                        \
      float s10 = 0.f, s11 = 0.f, s12 = 0.f, s13 = 0.f;                        \
      _Pragma("unroll")                                                        \
      for (int d4 = 0; d4 < 16; ++d4) {                                        \
          const float4 q0 = *reinterpret_cast<const float4*>(&qf[2 * ty][4 * d4]);     \
          const float4 q1 = *reinterpret_cast<const float4*>(&qf[2 * ty + 1][4 * d4]); \
          const float4 k0 = *reinterpret_cast<const float4*>(&KF[tx][4 * d4]);         \
          const float4 k1 = *reinterpret_cast<const float4*>(&KF[16 + tx][4 * d4]);    \
          const float4 k2 = *reinterpret_cast<const float4*>(&KF[32 + tx][4 * d4]);    \
          const float4 k3 = *reinterpret_cast<const float4*>(&KF[48 + tx][4 * d4]);    \
          s00 += q0.x*k0.x + q0.y*k0.y + q0.z*k0.z + q0.w*k0.w;                \
          s01 += q0.x*k1.x + q0.y*k1.y + q0.z*k1.z + q0.w*k1.w;                \
          s02 += q0.x*k2.x + q0.y*k2.y + q0.z*k2.z + q0.w*k2.w;                \
          s03 += q0.x*k3.x + q0.y*k3.y + q0.z*k3.z + q0.w*k3.w;                \
          s10 += q1.x*k0.x + q1.y*k0.y + q1.z*k0.z + q1.w*k0.w;                \
          s11 += q1.x*k1.x + q1.y*k1.y + q1.z*k1.z + q1.w*k1.w;                \
          s12 += q1.x*k2.x + q1.y*k2.y + q1.z*k2.z + q1.w*k2.w;                \
          s13 += q1.x*k3.x + q1.y*k3.y + q1.z*k3.z + q1.w*k3.w;                \
      }                                                                        \
      const unsigned long long m0 =                                            \
          rowcap_mask(s00, s01, s02, s03, r0 + 2 * ty,     (SB), tx, gsh, mrun0); \
      const unsigned long long m1 =                                            \
          rowcap_mask(s10, s11, s12, s13, r0 + 2 * ty + 1, (SB), tx, gsh, mrun1); \
      if (tx == 0) {                                                           \
          candmask[2 * ty][(SB)]     = m0;                                     \
          candmask[2 * ty + 1][(SB)] = m1; } }

__global__ __launch_bounds__(256) void argmin_kernel(
    const double* __restrict__ qd,
    const double* __restrict__ kd,
    const float*  __restrict__ vf,
    float* __restrict__ out)
{
    __shared__ float qf[QROWS][68];
    __shared__ float kfA[64][68];
    __shared__ float kfB[64][68];
    __shared__ unsigned long long candmask[QROWS][NSB];

    const int tid  = threadIdx.x;
    const int lane = tid & 63;
    const unsigned gsh = (unsigned)(lane & 48);   // 16-lane group base in ballot
    const int tx  = tid & 15;       // score cols 16j + tx (consecutive -> conflict-free)
    const int ty  = tid >> 4;       // score rows 2ty, 2ty+1
    const int b   = blockIdx.x;     // batch == XCD (gridDim.x = 8)
    const int byy = blockIdx.y;
    const int tb  = (byy < 32) ? byy : 95 - byy;   // co-CU pair work ~constant
    const int r0  = tb * QROWS;
    const int sb0 = tb >> 1;        // first s-block containing any future col

    // stage qf (fp64 -> fp32, coalesced)
    {
        const double* qsrc = qd + ((size_t)b * SEQ + r0) * HDIM;
        #pragma unroll
        for (int it = 0; it < 8; ++it) {
            const int idx = tid + it * 256;
            qf[idx >> 6][idx & 63] = (float)qsrc[(idx >> 6) * HDIM + (idx & 63)];
        }
    }

    const int c2 = tid & 31;
    const int rb = tid >> 5;

    float mrun0 = 3.0e38f, mrun1 = 3.0e38f;

    STAGE(kfA, sb0);
    __syncthreads();

    int sb = sb0;
    while (true) {
        if (sb + 1 < NSB) STAGE(kfB, sb + 1);
        BODY(kfA, sb);
        __syncthreads();
        ++sb;
        if (sb >= NSB) break;
        if (sb + 1 < NSB) STAGE(kfA, sb + 1);
        BODY(kfB, sb);
        __syncthreads();
        ++sb;
        if (sb >= NSB) break;
    }
    __syncthreads();

    // ---- refinement: 8 lanes per row walk the bitmasks, exact fp64 dots
    const int row = tid >> 3, l8 = tid & 7;
    const int rg  = r0 + row;
    int n = 0;
    double min1 = 1.0e300, min2 = 1.0e300;
    int amin = -1;
    const double* qrow = qd + ((size_t)b * SEQ + rg) * HDIM;
    for (int sbi = sb0; sbi < NSB; ++sbi) {
        unsigned long long m = candmask[row][sbi];
        while (m) {
            const int p = __ffsll((long long)m) - 1;
            m &= m - 1;
            const int col = sbi * 64 + p;
            if (col <= rg) continue;          // defense in depth: FUTURE only
            ++n;
            const double* krow = kd + ((size_t)b * SEQ + col) * HDIM;
            double part = 0.0;
            #pragma unroll
            for (int dd = 0; dd < 8; ++dd)
                part += qrow[8 * l8 + dd] * krow[8 * l8 + dd];
            #pragma unroll
            for (int off = 4; off > 0; off >>= 1)
                part += __shfl_xor(part, off, 8);
            if (part < min1) { min2 = min1; min1 = part; amin = col; }
            else if (part < min2) { min2 = part; }
        }
    }
    // honest (no sufficiently-negative future / empty future) or ambiguous tie
    // -> exact-row fallback via NaN sentinel in out[rg][0].
    const bool flag = (n == 0) || (min1 > -1e-10) || ((min2 - min1) < 1e-11);
    float* orow = out + ((size_t)b * SEQ + rg) * HDIM;
    if (flag) {
        if (l8 == 0) orow[0] = __uint_as_float(SENTINEL);
    } else {
        const float* vrow = vf + ((size_t)b * SEQ + amin) * HDIM;
        const float4 v0 = *reinterpret_cast<const float4*>(&vrow[8 * l8]);
        const float4 v1 = *reinterpret_cast<const float4*>(&vrow[8 * l8 + 4]);
        *reinterpret_cast<float4*>(&orow[8 * l8])     = v0;
        *reinterpret_cast<float4*>(&orow[8 * l8 + 4]) = v1;
    }
}

// ---------------------------------------------------------------- exact-row fallback
// One block PER ROW, grid (8, 2048): non-flagged blocks exit on a broadcast
// read; the ~2-4 flagged rows per batch run in PARALLEL (r13: they clustered in
// one block and serialized at ~65 us/row). Row eval uses wave-cooperative
// coalesced dots: 64 lanes load kd[col][lane] (one 512 B transaction) x q[lane].
__global__ __launch_bounds__(256) void exact_kernel(
    const double* __restrict__ qd,
    const double* __restrict__ kd,
    const float*  __restrict__ vf,
    float* __restrict__ out)
{
    __shared__ double qs[HDIM];
    __shared__ double lgbuf[SEQ];     // fp64 logits, 16 KB
    __shared__ float  pbuf[SEQ];
    __shared__ float  outacc[4][HDIM];
    __shared__ double mred[4];
    __shared__ float  psred[4];

    const int tid  = threadIdx.x;
    const int wid  = tid >> 6, lane = tid & 63;
    const int b    = blockIdx.x;      // batch == XCD
    const int rg   = blockIdx.y;      // row

    float* orow = out + ((size_t)b * SEQ + rg) * HDIM;
    if (__float_as_uint(orow[0]) != SENTINEL) return;   // uniform broadcast read

    if (tid < HDIM) qs[tid] = qd[((size_t)b * SEQ + rg) * HDIM + tid];
    __syncthreads();

    const double qv = qs[lane];
    const double* kb = kd + (size_t)b * SEQ * HDIM;
    const int cbase = 512 * wid;      // wave's column range

    for (int cc = 0; cc < 512; cc += 4) {
        const int c = cbase + cc;
        double p0 = kb[(size_t)(c + 0) * HDIM + lane] * qv;
        double p1 = kb[(size_t)(c + 1) * HDIM + lane] * qv;
        double p2 = kb[(size_t)(c + 2) * HDIM + lane] * qv;
        double p3 = kb[(size_t)(c + 3) * HDIM + lane] * qv;
        #pragma unroll
        for (int off = 32; off > 0; off >>= 1) {
            p0 += __shfl_xor(p0, off, 64);
            p1 += __shfl_xor(p1, off, 64);
            p2 += __shfl_xor(p2, off, 64);
            p3 += __shfl_xor(p3, off, 64);
        }
        if (lane == 0) {
            lgbuf[c]     = p0 * ((c     <= rg) ? 0.125 : MASKC);
            lgbuf[c + 1] = p1 * ((c + 1 <= rg) ? 0.125 : MASKC);
            lgbuf[c + 2] = p2 * ((c + 2 <= rg) ? 0.125 : MASKC);
            lgbuf[c + 3] = p3 * ((c + 3 <= rg) ? 0.125 : MASKC);
        }
    }
    __syncthreads();

    double mymax = -1.0e300;
    #pragma unroll
    for (int it = 0; it < 8; ++it)
        mymax = fmax(mymax, lgbuf[tid + it * 256]);
    #pragma unroll
    for (int off = 32; off > 0; off >>= 1)
        mymax = fmax(mymax, __shfl_xor(mymax, off, 64));
    if (lane == 0) mred[wid] = mymax;
    __syncthreads();
    const double M = fmax(fmax(mred[0], mred[1]), fmax(mred[2], mred[3]));

    float mypsum = 0.f;
    #pragma unroll
    for (int it = 0; it < 8; ++it) {
        const int col = tid + it * 256;
        const double dl = lgbuf[col] - M;
        const float p = (dl < -80.0) ? 0.f : (float)exp(dl);
        pbuf[col] = p;
        mypsum += p;
    }
    #pragma unroll
    for (int off = 32; off > 0; off >>= 1)
        mypsum += __shfl_xor(mypsum, off, 64);
    if (lane == 0) psred[wid] = mypsum;
    __syncthreads();
    const float PS = psred[0] + psred[1] + psred[2] + psred[3];

    const int d = tid & 63, chunk = tid >> 6;
    float acc = 0.f;
    for (int cc = 0; cc < 512; ++cc) {
        const int col = chunk * 512 + cc;
        acc += pbuf[col] * vf[((size_t)b * SEQ + col) * HDIM + d];
    }
    outacc[chunk][d] = acc;
    __syncthreads();
    if (tid < HDIM)
        orow[tid] = (outacc[0][tid] + outacc[1][tid] +
                     outacc[2][tid] + outacc[3][tid]) / PS;
}

extern "C" void kernel_launch(void* const* d_in, const int* in_sizes, int n_in,
                              void* d_out, int out_size, void* d_ws, size_t ws_size,
                              hipStream_t stream)
{
    const float* x  = (const float*)d_in[0];
    const float* Wk = (const float*)d_in[1];
    const float* Wq = (const float*)d_in[2];
    const float* Wv = (const float*)d_in[3];
    float* out = (float*)d_out;

    // workspace: q fp64 (8 MB) | k fp64 (8 MB) | v fp32 (4 MB) — proven 20 MB layout
    double* qd = (double*)d_ws;
    double* kd = qd + (size_t)BATCH * SEQ * HDIM;
    float*  vf = (float*)(kd + (size_t)BATCH * SEQ * HDIM);

    qkv_proj_kernel<<<dim3(512), dim3(256), 0, stream>>>(x, Wk, Wq, Wv, qd, kd, vf);
    argmin_kernel<<<dim3(8, 64), dim3(256), 0, stream>>>(qd, kd, vf, out);
    exact_kernel<<<dim3(8, SEQ), dim3(256), 0, stream>>>(qd, kd, vf, out);
}